// Round 1
// baseline (1012.984 us; speedup 1.0000x reference)
//
#include <hip/hip_runtime.h>
#include <stdint.h>

#define B_   2
#define T_   2048
#define D_   2048
#define H_   16
#define KV_  8
#define DH_  128
#define NMEM 1024
#define WWIN 256
#define KSEL 8
#define BT   (B_*T_)

__constant__ const float kScale = 0.08838834764831845f; // DH^-0.5

typedef __attribute__((ext_vector_type(8))) short s16x8;
typedef __attribute__((ext_vector_type(4))) float f32x4;

__device__ inline unsigned short f2bf(float f) {
  union { float f; unsigned int u; } c; c.f = f;
  unsigned int u = c.u;
  unsigned int r = u + 0x7fffu + ((u >> 16) & 1u);
  return (unsigned short)(r >> 16);
}
__device__ inline float bf2f(unsigned short v) {
  union { unsigned int u; float f; } c; c.u = ((unsigned int)v) << 16;
  return c.f;
}
__device__ inline f32x4 fzero4() { f32x4 v; v[0]=0.f; v[1]=0.f; v[2]=0.f; v[3]=0.f; return v; }

// ---------------- fp32 -> bf16 conversion (float4 wide) ----------------
__global__ __launch_bounds__(256) void conv_kernel(const float* __restrict__ src,
                                                   unsigned short* __restrict__ dst, int n) {
  int i = blockIdx.x * 256 + threadIdx.x;
  if (i * 4 >= n) return;
  float4 v = ((const float4*)src)[i];
  uint2 o;
  o.x = (unsigned)f2bf(v.x) | ((unsigned)f2bf(v.y) << 16);
  o.y = (unsigned)f2bf(v.z) | ((unsigned)f2bf(v.w) << 16);
  ((uint2*)dst)[i] = o;
}

// ---------------- bf16 GEMM: C[M,N] = A[M,K] @ B[N,K]^T ----------------
// MODE 0: write bf16 C.  MODE 1: dout = g[row]*acc + (1-g[row])*dout (fp32, in place)
template<int MODE>
__global__ __launch_bounds__(256) void gemm_bt(const unsigned short* __restrict__ A,
                                               const unsigned short* __restrict__ Bw,
                                               int N, int K,
                                               unsigned short* __restrict__ Cb,
                                               const float* __restrict__ g,
                                               float* __restrict__ dout) {
  __shared__ __align__(16) unsigned short sA[128 * 32];
  __shared__ __align__(16) unsigned short sB[128 * 32];
  const int tid = threadIdx.x;
  const int wv = tid >> 6, lane = tid & 63;
  const int m0 = blockIdx.y * 128, n0 = blockIdx.x * 128;
  const int wr = wv >> 1, wc = wv & 1;
  const int l15 = lane & 15, lg = lane >> 4;
  const int rowA = tid >> 2;
  const int colB = (tid & 3) * 16; // bytes
  f32x4 acc[4][4];
#pragma unroll
  for (int mi = 0; mi < 4; ++mi)
#pragma unroll
    for (int ni = 0; ni < 4; ++ni) acc[mi][ni] = fzero4();

  char* sAc = (char*)sA;
  char* sBc = (char*)sB;
  for (int k0 = 0; k0 < K; k0 += 32) {
#pragma unroll
    for (int e = 0; e < 2; ++e) {
      const char* ga = (const char*)(A + ((size_t)(m0 + rowA + e * 64) * K + k0)) + colB;
      __builtin_amdgcn_global_load_lds((const __attribute__((address_space(1))) void*)ga,
          (__attribute__((address_space(3))) void*)(sAc + e * 4096 + wv * 1024), 16, 0, 0);
      const char* gb = (const char*)(Bw + ((size_t)(n0 + rowA + e * 64) * K + k0)) + colB;
      __builtin_amdgcn_global_load_lds((const __attribute__((address_space(1))) void*)gb,
          (__attribute__((address_space(3))) void*)(sBc + e * 4096 + wv * 1024), 16, 0, 0);
    }
    __syncthreads();
    s16x8 af[4], bf_[4];
#pragma unroll
    for (int mi = 0; mi < 4; ++mi)
      af[mi] = *(const s16x8*)&sA[(wr * 64 + mi * 16 + l15) * 32 + lg * 8];
#pragma unroll
    for (int ni = 0; ni < 4; ++ni)
      bf_[ni] = *(const s16x8*)&sB[(wc * 64 + ni * 16 + l15) * 32 + lg * 8];
#pragma unroll
    for (int mi = 0; mi < 4; ++mi)
#pragma unroll
      for (int ni = 0; ni < 4; ++ni)
        acc[mi][ni] = __builtin_amdgcn_mfma_f32_16x16x32_bf16(af[mi], bf_[ni], acc[mi][ni], 0, 0, 0);
    __syncthreads();
  }
#pragma unroll
  for (int mi = 0; mi < 4; ++mi)
#pragma unroll
    for (int ni = 0; ni < 4; ++ni)
#pragma unroll
      for (int j = 0; j < 4; ++j) {
        int row_g = m0 + wr * 64 + mi * 16 + lg * 4 + j;
        int col_g = n0 + wc * 64 + ni * 16 + l15;
        float v = acc[mi][ni][j];
        if constexpr (MODE == 0) {
          Cb[(size_t)row_g * N + col_g] = f2bf(v);
        } else {
          float gv = g[row_g];
          size_t o = (size_t)row_g * N + col_g;
          float om = dout[o];
          dout[o] = gv * v + (1.f - gv) * om;
        }
      }
}

// ---------------- RoPE (bf16 in/out) ----------------
__global__ __launch_bounds__(256) void rope_kernel(const unsigned short* __restrict__ src,
                                                   unsigned short* __restrict__ dst,
                                                   const float* __restrict__ cosp,
                                                   const float* __restrict__ sinp,
                                                   int logw, int total) {
  int i = blockIdx.x * 256 + threadIdx.x;
  if (i >= total) return;
  int width = 1 << logw;
  int row = i >> logw;
  int c = i & (width - 1);
  int d = c & 127;
  int b = row >> 11, t = row & 2047;
  float cv = cosp[((size_t)b * T_ + t) * DH_ + d];
  float sv = sinp[((size_t)b * T_ + t) * DH_ + d];
  float x = bf2f(src[i]);
  float xr = (d < 64) ? -bf2f(src[i + 64]) : bf2f(src[i - 64]);
  dst[i] = f2bf(x * cv + xr * sv);
}

// ---------------- C/S accumulation: C[b,d,j] = sum_t cos[b,t,d]*hs[b,t,j] ----------------
__global__ __launch_bounds__(256) void cs_kernel(const float* __restrict__ hs,
                                                 const float* __restrict__ cosp,
                                                 const float* __restrict__ sinp,
                                                 float* __restrict__ Cm, float* __restrict__ Sm) {
  __shared__ float csL[32][16];
  __shared__ float snL[32][16];
  __shared__ __align__(16) float hsL[32][64];
  int tid = threadIdx.x;
  int j0 = blockIdx.x * 64, d0 = blockIdx.y * 16, b = blockIdx.z;
  int dd = tid & 15, j4 = tid >> 4;
  float aC[4] = {0.f, 0.f, 0.f, 0.f}, aS[4] = {0.f, 0.f, 0.f, 0.f};
  for (int t0 = 0; t0 < T_; t0 += 32) {
    int tt0 = tid >> 4, col = tid & 15;
#pragma unroll
    for (int r = 0; r < 2; ++r) {
      int trow = tt0 + r * 16;
      size_t cbase = ((size_t)b * T_ + t0 + trow) * DH_ + d0 + col;
      csL[trow][col] = cosp[cbase];
      snL[trow][col] = sinp[cbase];
      *(float4*)&hsL[trow][col * 4] =
          *(const float4*)&hs[((size_t)b * T_ + t0 + trow) * D_ + j0 + col * 4];
    }
    __syncthreads();
#pragma unroll 8
    for (int tt = 0; tt < 32; ++tt) {
      float c = csL[tt][dd], s = snL[tt][dd];
      const float* hp = &hsL[tt][j4 * 4];
#pragma unroll
      for (int e = 0; e < 4; ++e) { float hv = hp[e]; aC[e] += c * hv; aS[e] += s * hv; }
    }
    __syncthreads();
  }
  size_t o = ((size_t)b * DH_ + d0 + dd) * D_ + j0 + j4 * 4;
  *(float4*)&Cm[o] = make_float4(aC[0], aC[1], aC[2], aC[3]);
  *(float4*)&Sm[o] = make_float4(aS[0], aS[1], aS[2], aS[3]);
}

// ---------------- q_chunk[b,h,d] via C/S (exact fp32) ----------------
__global__ __launch_bounds__(256) void qchunk_kernel(const float* __restrict__ Wq,
                                                     const float* __restrict__ Cm,
                                                     const float* __restrict__ Sm,
                                                     float* __restrict__ qc) {
  int gid = blockIdx.x * 256 + threadIdx.x;
  int wid = gid >> 6, lane = gid & 63;
  int b = wid >> 11, rem = wid & 2047;
  int h = rem >> 7, d = rem & 127;
  const float* crow = Cm + ((size_t)b * DH_ + d) * D_;
  const float* srow = Sm + ((size_t)b * DH_ + d) * D_;
  const float* w1 = Wq + (size_t)(h * DH_ + d) * D_;
  int dp = (d < 64) ? d + 64 : d - 64;
  float sgn = (d < 64) ? -1.f : 1.f;
  const float* w2 = Wq + (size_t)(h * DH_ + dp) * D_;
  float a1 = 0.f, a2 = 0.f;
  for (int j = lane; j < D_; j += 64) { a1 += w1[j] * crow[j]; a2 += w2[j] * srow[j]; }
#pragma unroll
  for (int off = 1; off < 64; off <<= 1) { a1 += __shfl_xor(a1, off); a2 += __shfl_xor(a2, off); }
  if (lane == 0) qc[wid] = (a1 + sgn * a2) * (1.f / (float)T_);
}

// ---------------- selection: z = Wk_head^T qc; sim = z.mem; top8; gather-project ----------------
__global__ __launch_bounds__(256) void sel_kernel(const float* __restrict__ qc,
                                                  const float* __restrict__ Wk,
                                                  const float* __restrict__ Wv,
                                                  const float* __restrict__ mem,
                                                  float* __restrict__ kshp,
                                                  float* __restrict__ vshp) {
  __shared__ __align__(16) float4 z4[512];
  __shared__ float sim[1024];
  __shared__ float qcl[128];
  __shared__ float rv[256];
  __shared__ int ri[256];
  __shared__ int seln[8];
  int tid = threadIdx.x;
  int h = blockIdx.x, b = blockIdx.y;
  int kvh = h >> 1;
  if (tid < 128) qcl[tid] = qc[((size_t)b * H_ + h) * DH_ + tid];
  __syncthreads();
  // phase A: z[j] = sum_d qc[d] * Wk[kvh*128+d][j]
  {
    float accz[8] = {0.f,0.f,0.f,0.f,0.f,0.f,0.f,0.f};
    for (int d = 0; d < 128; ++d) {
      float q = qcl[d];
      const float* wr = Wk + (size_t)(kvh * DH_ + d) * D_;
#pragma unroll
      for (int r = 0; r < 8; ++r) accz[r] += q * wr[tid + r * 256];
    }
    float* z = (float*)z4;
#pragma unroll
    for (int r = 0; r < 8; ++r) z[tid + r * 256] = accz[r];
  }
  __syncthreads();
  // phase B: sim[n] = scale * z . mem[b,n,:]
  int wv = tid >> 6, lane = tid & 63;
  for (int n = wv; n < NMEM; n += 4) {
    const float4* mrow = (const float4*)(mem + ((size_t)b * NMEM + n) * D_);
    float acc = 0.f;
#pragma unroll
    for (int it = 0; it < 8; ++it) {
      float4 zz = z4[lane + it * 64];
      float4 mm = mrow[lane + it * 64];
      acc += zz.x * mm.x + zz.y * mm.y + zz.z * mm.z + zz.w * mm.w;
    }
#pragma unroll
    for (int off = 1; off < 64; off <<= 1) acc += __shfl_xor(acc, off);
    if (lane == 0) sim[n] = acc * kScale;
  }
  __syncthreads();
  // phase C: top-8 (ties -> lowest index, matching lax.top_k)
  for (int kk = 0; kk < 8; ++kk) {
    float bv = -INFINITY; int bi = 0x7fffffff;
#pragma unroll
    for (int r = 0; r < 4; ++r) {
      int i = tid + r * 256;
      float v = sim[i];
      if (v > bv || (v == bv && i < bi)) { bv = v; bi = i; }
    }
    rv[tid] = bv; ri[tid] = bi;
    __syncthreads();
    for (int s = 128; s > 0; s >>= 1) {
      if (tid < s) {
        float v2 = rv[tid + s]; int i2 = ri[tid + s];
        if (v2 > rv[tid] || (v2 == rv[tid] && i2 < ri[tid])) { rv[tid] = v2; ri[tid] = i2; }
      }
      __syncthreads();
    }
    if (tid == 0) { seln[kk] = ri[0]; sim[ri[0]] = -INFINITY; }
    __syncthreads();
  }
  // phase E: k_sh / v_sh = W_head @ mem[selected]   (fp32)
  int half = tid >> 7, d = tid & 127;
  const float* wrow = (half ? Wv : Wk) + (size_t)(kvh * DH_ + d) * D_;
  int nsel[8];
#pragma unroll
  for (int kk = 0; kk < 8; ++kk) nsel[kk] = seln[kk];
  float acc[8] = {0.f,0.f,0.f,0.f,0.f,0.f,0.f,0.f};
  const float* mb = mem + (size_t)b * NMEM * D_;
  for (int j = 0; j < D_; ++j) {
    float w = wrow[j];
#pragma unroll
    for (int kk = 0; kk < 8; ++kk) acc[kk] += w * mb[(size_t)nsel[kk] * D_ + j];
  }
  float* outp = (half ? vshp : kshp) + ((size_t)b * H_ + h) * KSEL * DH_;
#pragma unroll
  for (int kk = 0; kk < 8; ++kk) outp[kk * DH_ + d] = acc[kk];
}

// ---------------- memory-branch attention: o_mem -> d_out (fp32) ----------------
__global__ __launch_bounds__(256) void memattn_kernel(const unsigned short* __restrict__ qbf,
                                                      const float* __restrict__ ksh,
                                                      const float* __restrict__ vsh,
                                                      float* __restrict__ dout) {
  __shared__ float kl[8][128];
  __shared__ float vl[8][128];
  int tid = threadIdx.x;
  int b = blockIdx.z, h = blockIdx.y, t = blockIdx.x * 256 + tid;
  const float* ks = ksh + ((size_t)b * H_ + h) * KSEL * DH_;
  const float* vs = vsh + ((size_t)b * H_ + h) * KSEL * DH_;
#pragma unroll
  for (int r = 0; r < 4; ++r) {
    int i = tid + r * 256;
    ((float*)kl)[i] = ks[i];
    ((float*)vl)[i] = vs[i];
  }
  __syncthreads();
  float sc[8] = {0.f,0.f,0.f,0.f,0.f,0.f,0.f,0.f};
  const unsigned short* qr = qbf + (size_t)(b * T_ + t) * D_ + h * DH_;
  for (int c = 0; c < 4; ++c) {
    const s16x8* qp = (const s16x8*)(qr + c * 32);
#pragma unroll
    for (int u = 0; u < 4; ++u) {
      s16x8 q8 = qp[u];
#pragma unroll
      for (int e = 0; e < 8; ++e) {
        float qv = bf2f((unsigned short)q8[e]);
        int d = c * 32 + u * 8 + e;
#pragma unroll
        for (int kk = 0; kk < 8; ++kk) sc[kk] += qv * kl[kk][d];
      }
    }
  }
  float sm[8], mx = -INFINITY;
#pragma unroll
  for (int kk = 0; kk < 8; ++kk) { sm[kk] = sc[kk] * kScale; mx = fmaxf(mx, sm[kk]); }
  float sum = 0.f;
#pragma unroll
  for (int kk = 0; kk < 8; ++kk) { sm[kk] = __expf(sm[kk] - mx); sum += sm[kk]; }
  float inv = 1.f / sum;
#pragma unroll
  for (int kk = 0; kk < 8; ++kk) sm[kk] *= inv;
  float* orow = dout + (size_t)(b * T_ + t) * D_ + h * DH_;
  for (int d = 0; d < 128; d += 4) {
    float4 o;
    o.x = 0.f; o.y = 0.f; o.z = 0.f; o.w = 0.f;
#pragma unroll
    for (int kk = 0; kk < 8; ++kk) {
      float w = sm[kk];
      o.x += w * vl[kk][d + 0];
      o.y += w * vl[kk][d + 1];
      o.z += w * vl[kk][d + 2];
      o.w += w * vl[kk][d + 3];
    }
    *(float4*)(orow + d) = o;
  }
}

// ---------------- gate: g = sigmoid(hs . Wg + bg) ----------------
__global__ __launch_bounds__(256) void gate_kernel(const float* __restrict__ hs,
                                                   const float* __restrict__ Wg,
                                                   const float* __restrict__ bg,
                                                   float* __restrict__ g) {
  int gid = blockIdx.x * 256 + threadIdx.x;
  int row = gid >> 6, lane = gid & 63;
  const float4* hr = (const float4*)(hs + (size_t)row * D_);
  const float4* wg4 = (const float4*)Wg;
  float acc = 0.f;
#pragma unroll
  for (int it = 0; it < 8; ++it) {
    float4 hv = hr[lane + it * 64], wv = wg4[lane + it * 64];
    acc += hv.x * wv.x + hv.y * wv.y + hv.z * wv.z + hv.w * wv.w;
  }
#pragma unroll
  for (int off = 1; off < 64; off <<= 1) acc += __shfl_xor(acc, off);
  if (lane == 0) g[row] = 1.f / (1.f + __expf(-(acc + bg[0])));
}

// ---------------- local sliding-window attention (flash, per-wave 16 rows) ----------------
__global__ __launch_bounds__(256) void localattn_kernel(const unsigned short* __restrict__ qbf,
                                                        const unsigned short* __restrict__ kbf,
                                                        const unsigned short* __restrict__ vbf,
                                                        unsigned short* __restrict__ olocal) {
  __shared__ __align__(16) unsigned short pl[4][16][40];
  const int tid = threadIdx.x;
  const int w = tid >> 6, lane = tid & 63;
  const int tb = blockIdx.x * 64;
  const int h = blockIdx.y, b = blockIdx.z;
  const int kvh = h >> 1;
  const int t0 = tb + w * 16;
  const int l15 = lane & 15, lg = lane >> 4;

  s16x8 qf[4];
  {
    const unsigned short* qb = qbf + ((size_t)(b * T_ + t0 + l15) * D_) + h * DH_ + lg * 8;
#pragma unroll
    for (int kb = 0; kb < 4; ++kb) qf[kb] = *(const s16x8*)(qb + kb * 32);
  }
  f32x4 of[8];
#pragma unroll
  for (int nb = 0; nb < 8; ++nb) of[nb] = fzero4();
  float m_r[4] = {-INFINITY, -INFINITY, -INFINITY, -INFINITY};
  float l_r[4] = {0.f, 0.f, 0.f, 0.f};

  int sstart = t0 - (WWIN - 1);
  if (sstart < 0) sstart = 0;
  sstart &= ~31;
  for (int s0 = sstart; s0 <= t0 + 15; s0 += 32) {
    f32x4 sc[2];
    sc[0] = fzero4(); sc[1] = fzero4();
    const unsigned short* kb0 = kbf + ((size_t)(b * T_ + s0 + l15) * (KV_ * DH_)) + kvh * DH_ + lg * 8;
#pragma unroll
    for (int cb = 0; cb < 2; ++cb) {
#pragma unroll
      for (int kb = 0; kb < 4; ++kb) {
        s16x8 kf = *(const s16x8*)(kb0 + (size_t)cb * 16 * (KV_ * DH_) + kb * 32);
        sc[cb] = __builtin_amdgcn_mfma_f32_16x16x32_bf16(qf[kb], kf, sc[cb], 0, 0, 0);
      }
    }
    float pv[2][4];
#pragma unroll
    for (int j = 0; j < 4; ++j) {
      int t = t0 + lg * 4 + j;
      int s_a = s0 + l15, s_b = s_a + 16;
      float va = sc[0][j] * kScale;
      float vb = sc[1][j] * kScale;
      va = (s_a <= t && s_a + (WWIN - 1) >= t) ? va : -INFINITY;
      vb = (s_b <= t && s_b + (WWIN - 1) >= t) ? vb : -INFINITY;
      float mx = fmaxf(va, vb);
#pragma unroll
      for (int off = 1; off < 16; off <<= 1) mx = fmaxf(mx, __shfl_xor(mx, off));
      float mn = fmaxf(m_r[j], mx);
      float alpha, pa, pb;
      if (mn == -INFINITY) { alpha = 1.f; pa = 0.f; pb = 0.f; }
      else {
        alpha = __expf(m_r[j] - mn);
        pa = __expf(va - mn);
        pb = __expf(vb - mn);
      }
      m_r[j] = mn;
      float rs = pa + pb;
#pragma unroll
      for (int off = 1; off < 16; off <<= 1) rs += __shfl_xor(rs, off);
      l_r[j] = l_r[j] * alpha + rs;
#pragma unroll
      for (int nb = 0; nb < 8; ++nb) of[nb][j] *= alpha;
      pv[0][j] = pa; pv[1][j] = pb;
    }
#pragma unroll
    for (int cb = 0; cb < 2; ++cb)
#pragma unroll
      for (int j = 0; j < 4; ++j)
        pl[w][lg * 4 + j][cb * 16 + l15] = f2bf(pv[cb][j]);
    asm volatile("s_waitcnt lgkmcnt(0)" ::: "memory");
    s16x8 pa8 = *(const s16x8*)&pl[w][l15][lg * 8];
    const unsigned short* vb0 = vbf + ((size_t)(b * T_ + s0 + lg * 8) * (KV_ * DH_)) + kvh * DH_ + l15;
#pragma unroll
    for (int nb = 0; nb < 8; ++nb) {
      s16x8 vf;
#pragma unroll
      for (int jj = 0; jj < 8; ++jj) vf[jj] = (short)vb0[(size_t)jj * (KV_ * DH_) + nb * 16];
      of[nb] = __builtin_amdgcn_mfma_f32_16x16x32_bf16(pa8, vf, of[nb], 0, 0, 0);
    }
  }
  float inv[4];
#pragma unroll
  for (int j = 0; j < 4; ++j) inv[j] = 1.f / l_r[j];
#pragma unroll
  for (int nb = 0; nb < 8; ++nb)
#pragma unroll
    for (int j = 0; j < 4; ++j) {
      int t = t0 + lg * 4 + j;
      olocal[(size_t)(b * T_ + t) * D_ + h * DH_ + nb * 16 + l15] = f2bf(of[nb][j] * inv[j]);
    }
}

// ---------------- host launcher ----------------
extern "C" void kernel_launch(void* const* d_in, const int* in_sizes, int n_in,
                              void* d_out, int out_size, void* d_ws, size_t ws_size,
                              hipStream_t stream) {
  const float* hs   = (const float*)d_in[0];
  const float* cosp = (const float*)d_in[1];
  const float* sinp = (const float*)d_in[2];
  const float* mem  = (const float*)d_in[3];
  const float* Wq   = (const float*)d_in[4];
  const float* Wk   = (const float*)d_in[5];
  const float* Wv   = (const float*)d_in[6];
  const float* Wo   = (const float*)d_in[7];
  const float* Wg   = (const float*)d_in[8];
  const float* bg   = (const float*)d_in[9];
  float* out = (float*)d_out;

  char* p = (char*)d_ws;
  auto alloc = [&](size_t bytes) { char* r = p; p += (bytes + 255) & ~(size_t)255; return r; };
  unsigned short* hs_bf = (unsigned short*)alloc((size_t)BT * D_ * 2);
  unsigned short* q_raw = (unsigned short*)alloc((size_t)BT * D_ * 2);   // reused as o_local
  unsigned short* q_bf  = (unsigned short*)alloc((size_t)BT * D_ * 2);
  unsigned short* k_raw = (unsigned short*)alloc((size_t)BT * KV_ * DH_ * 2); // reused for C/S
  unsigned short* k_bf  = (unsigned short*)alloc((size_t)BT * KV_ * DH_ * 2);
  unsigned short* v_bf  = (unsigned short*)alloc((size_t)BT * KV_ * DH_ * 2);
  unsigned short* Wq_bf = (unsigned short*)alloc((size_t)D_ * D_ * 2);
  unsigned short* Wk_bf = (unsigned short*)alloc((size_t)KV_ * DH_ * D_ * 2);
  unsigned short* Wv_bf = (unsigned short*)alloc((size_t)KV_ * DH_ * D_ * 2);
  unsigned short* Wo_bf = (unsigned short*)alloc((size_t)D_ * D_ * 2);
  float* qc   = (float*)alloc((size_t)B_ * H_ * DH_ * 4);
  float* ksh  = (float*)alloc((size_t)B_ * H_ * KSEL * DH_ * 4);
  float* vsh  = (float*)alloc((size_t)B_ * H_ * KSEL * DH_ * 4);
  float* gbuf = (float*)alloc((size_t)BT * 4);
  float* Cm = (float*)k_raw;                       // after rope-k, k_raw is dead
  float* Sm = Cm + (size_t)B_ * DH_ * D_;

  unsigned short* o_local = q_raw;                 // after rope-q, q_raw is dead

  // 1) fp32 -> bf16 conversions
  conv_kernel<<<(BT * D_ / 4 + 255) / 256, 256, 0, stream>>>(hs, hs_bf, BT * D_);
  conv_kernel<<<(D_ * D_ / 4 + 255) / 256, 256, 0, stream>>>(Wq, Wq_bf, D_ * D_);
  conv_kernel<<<(KV_ * DH_ * D_ / 4 + 255) / 256, 256, 0, stream>>>(Wk, Wk_bf, KV_ * DH_ * D_);
  conv_kernel<<<(KV_ * DH_ * D_ / 4 + 255) / 256, 256, 0, stream>>>(Wv, Wv_bf, KV_ * DH_ * D_);
  conv_kernel<<<(D_ * D_ / 4 + 255) / 256, 256, 0, stream>>>(Wo, Wo_bf, D_ * D_);

  // 2) projections (bf16 MFMA)
  gemm_bt<0><<<dim3(D_ / 128, BT / 128), 256, 0, stream>>>(hs_bf, Wq_bf, D_, D_, q_raw, nullptr, nullptr);
  gemm_bt<0><<<dim3(KV_ * DH_ / 128, BT / 128), 256, 0, stream>>>(hs_bf, Wk_bf, KV_ * DH_, D_, k_raw, nullptr, nullptr);
  gemm_bt<0><<<dim3(KV_ * DH_ / 128, BT / 128), 256, 0, stream>>>(hs_bf, Wv_bf, KV_ * DH_, D_, v_bf, nullptr, nullptr);

  // 3) RoPE
  rope_kernel<<<BT * D_ / 256, 256, 0, stream>>>(q_raw, q_bf, cosp, sinp, 11, BT * D_);
  rope_kernel<<<BT * KV_ * DH_ / 256, 256, 0, stream>>>(k_raw, k_bf, cosp, sinp, 10, BT * KV_ * DH_);

  // 4) exact-fp32 selection path
  cs_kernel<<<dim3(D_ / 64, DH_ / 16, B_), 256, 0, stream>>>(hs, cosp, sinp, Cm, Sm);
  qchunk_kernel<<<(B_ * H_ * DH_) / 4, 256, 0, stream>>>(Wq, Cm, Sm, qc);
  sel_kernel<<<dim3(H_, B_), 256, 0, stream>>>(qc, Wk, Wv, mem, ksh, vsh);

  // 5) memory-branch attention -> d_out (fp32 o_mem)
  memattn_kernel<<<dim3(T_ / 256, H_, B_), 256, 0, stream>>>(q_bf, ksh, vsh, out);

  // 6) gate
  gate_kernel<<<BT / 4, 256, 0, stream>>>(hs, Wg, bg, gbuf);

  // 7) local sliding-window attention
  localattn_kernel<<<dim3(T_ / 64, H_, B_), 256, 0, stream>>>(q_bf, k_bf, v_bf, o_local);

  // 8) Wo projection + final combine (reads o_mem from d_out, writes final in place)
  gemm_bt<1><<<dim3(D_ / 128, BT / 128), 256, 0, stream>>>(o_local, Wo_bf, D_, D_, nullptr, gbuf, out);
}

// Round 3
// 681.484 us; speedup vs baseline: 1.4864x; 1.4864x over previous
//
#include <hip/hip_runtime.h>
#include <stdint.h>

#define B_   2
#define T_   2048
#define D_   2048
#define H_   16
#define KV_  8
#define DH_  128
#define NMEM 1024
#define WWIN 256
#define KSEL 8
#define BT   (B_*T_)

__constant__ const float kScale = 0.08838834764831845f; // DH^-0.5

typedef __attribute__((ext_vector_type(8))) short s16x8;
typedef __attribute__((ext_vector_type(4))) float f32x4;

__device__ inline unsigned short f2bf(float f) {
  union { float f; unsigned int u; } c; c.f = f;
  unsigned int u = c.u;
  unsigned int r = u + 0x7fffu + ((u >> 16) & 1u);
  return (unsigned short)(r >> 16);
}
__device__ inline float bf2f(unsigned short v) {
  union { unsigned int u; float f; } c; c.u = ((unsigned int)v) << 16;
  return c.f;
}
__device__ inline f32x4 fzero4() { f32x4 v; v[0]=0.f; v[1]=0.f; v[2]=0.f; v[3]=0.f; return v; }

// ---------------- fp32 -> bf16 conversion (float4 wide) ----------------
__global__ __launch_bounds__(256) void conv_kernel(const float* __restrict__ src,
                                                   unsigned short* __restrict__ dst, int n) {
  int i = blockIdx.x * 256 + threadIdx.x;
  if (i * 4 >= n) return;
  float4 v = ((const float4*)src)[i];
  uint2 o;
  o.x = (unsigned)f2bf(v.x) | ((unsigned)f2bf(v.y) << 16);
  o.y = (unsigned)f2bf(v.z) | ((unsigned)f2bf(v.w) << 16);
  ((uint2*)dst)[i] = o;
}

// ---------------- bf16 GEMM: C[M,N] = A[M,K] @ B[N,K]^T ----------------
// MODE 0: write bf16 C.
// MODE 1: dout = g[row]*acc + (1-g[row])*bf2f(omem[o])   (d_out pure write)
template<int MODE>
__global__ __launch_bounds__(256) void gemm_bt(const unsigned short* __restrict__ A,
                                               const unsigned short* __restrict__ Bw,
                                               int N, int K,
                                               unsigned short* __restrict__ Cb,
                                               const float* __restrict__ g,
                                               const unsigned short* __restrict__ omem,
                                               float* __restrict__ dout) {
  __shared__ __align__(16) unsigned short sA[128 * 32];
  __shared__ __align__(16) unsigned short sB[128 * 32];
  const int tid = threadIdx.x;
  const int wv = tid >> 6, lane = tid & 63;
  const int m0 = blockIdx.y * 128, n0 = blockIdx.x * 128;
  const int wr = wv >> 1, wc = wv & 1;
  const int l15 = lane & 15, lg = lane >> 4;
  const int rowA = tid >> 2;
  const int colB = (tid & 3) * 16; // bytes
  f32x4 acc[4][4];
#pragma unroll
  for (int mi = 0; mi < 4; ++mi)
#pragma unroll
    for (int ni = 0; ni < 4; ++ni) acc[mi][ni] = fzero4();

  char* sAc = (char*)sA;
  char* sBc = (char*)sB;
  for (int k0 = 0; k0 < K; k0 += 32) {
#pragma unroll
    for (int e = 0; e < 2; ++e) {
      const char* ga = (const char*)(A + ((size_t)(m0 + rowA + e * 64) * K + k0)) + colB;
      __builtin_amdgcn_global_load_lds((const __attribute__((address_space(1))) void*)ga,
          (__attribute__((address_space(3))) void*)(sAc + e * 4096 + wv * 1024), 16, 0, 0);
      const char* gb = (const char*)(Bw + ((size_t)(n0 + rowA + e * 64) * K + k0)) + colB;
      __builtin_amdgcn_global_load_lds((const __attribute__((address_space(1))) void*)gb,
          (__attribute__((address_space(3))) void*)(sBc + e * 4096 + wv * 1024), 16, 0, 0);
    }
    __syncthreads();
    s16x8 af[4], bf_[4];
#pragma unroll
    for (int mi = 0; mi < 4; ++mi)
      af[mi] = *(const s16x8*)&sA[(wr * 64 + mi * 16 + l15) * 32 + lg * 8];
#pragma unroll
    for (int ni = 0; ni < 4; ++ni)
      bf_[ni] = *(const s16x8*)&sB[(wc * 64 + ni * 16 + l15) * 32 + lg * 8];
#pragma unroll
    for (int mi = 0; mi < 4; ++mi)
#pragma unroll
      for (int ni = 0; ni < 4; ++ni)
        acc[mi][ni] = __builtin_amdgcn_mfma_f32_16x16x32_bf16(af[mi], bf_[ni], acc[mi][ni], 0, 0, 0);
    __syncthreads();
  }
#pragma unroll
  for (int mi = 0; mi < 4; ++mi)
#pragma unroll
    for (int ni = 0; ni < 4; ++ni)
#pragma unroll
      for (int j = 0; j < 4; ++j) {
        int row_g = m0 + wr * 64 + mi * 16 + lg * 4 + j;
        int col_g = n0 + wc * 64 + ni * 16 + l15;
        float v = acc[mi][ni][j];
        if constexpr (MODE == 0) {
          Cb[(size_t)row_g * N + col_g] = f2bf(v);
        } else {
          float gv = g[row_g];
          size_t o = (size_t)row_g * N + col_g;
          float om = bf2f(omem[o]);
          dout[o] = gv * v + (1.f - gv) * om;
        }
      }
}

// ---------------- RoPE (bf16 in/out) ----------------
__global__ __launch_bounds__(256) void rope_kernel(const unsigned short* __restrict__ src,
                                                   unsigned short* __restrict__ dst,
                                                   const float* __restrict__ cosp,
                                                   const float* __restrict__ sinp,
                                                   int logw, int total) {
  int i = blockIdx.x * 256 + threadIdx.x;
  if (i >= total) return;
  int width = 1 << logw;
  int row = i >> logw;
  int c = i & (width - 1);
  int d = c & 127;
  int b = row >> 11, t = row & 2047;
  float cv = cosp[((size_t)b * T_ + t) * DH_ + d];
  float sv = sinp[((size_t)b * T_ + t) * DH_ + d];
  float x = bf2f(src[i]);
  float xr = (d < 64) ? -bf2f(src[i + 64]) : bf2f(src[i - 64]);
  dst[i] = f2bf(x * cv + xr * sv);
}

// ---------------- C/S accumulation: C[b,d,j] = sum_t cos[b,t,d]*hs[b,t,j] ----------------
__global__ __launch_bounds__(256) void cs_kernel(const float* __restrict__ hs,
                                                 const float* __restrict__ cosp,
                                                 const float* __restrict__ sinp,
                                                 float* __restrict__ Cm, float* __restrict__ Sm) {
  __shared__ float csL[32][16];
  __shared__ float snL[32][16];
  __shared__ __align__(16) float hsL[32][64];
  int tid = threadIdx.x;
  int j0 = blockIdx.x * 64, d0 = blockIdx.y * 16, b = blockIdx.z;
  int dd = tid & 15, j4 = tid >> 4;
  float aC[4] = {0.f, 0.f, 0.f, 0.f}, aS[4] = {0.f, 0.f, 0.f, 0.f};
  for (int t0 = 0; t0 < T_; t0 += 32) {
    int tt0 = tid >> 4, col = tid & 15;
#pragma unroll
    for (int r = 0; r < 2; ++r) {
      int trow = tt0 + r * 16;
      size_t cbase = ((size_t)b * T_ + t0 + trow) * DH_ + d0 + col;
      csL[trow][col] = cosp[cbase];
      snL[trow][col] = sinp[cbase];
      *(float4*)&hsL[trow][col * 4] =
          *(const float4*)&hs[((size_t)b * T_ + t0 + trow) * D_ + j0 + col * 4];
    }
    __syncthreads();
#pragma unroll 8
    for (int tt = 0; tt < 32; ++tt) {
      float c = csL[tt][dd], s = snL[tt][dd];
      const float* hp = &hsL[tt][j4 * 4];
#pragma unroll
      for (int e = 0; e < 4; ++e) { float hv = hp[e]; aC[e] += c * hv; aS[e] += s * hv; }
    }
    __syncthreads();
  }
  size_t o = ((size_t)b * DH_ + d0 + dd) * D_ + j0 + j4 * 4;
  *(float4*)&Cm[o] = make_float4(aC[0], aC[1], aC[2], aC[3]);
  *(float4*)&Sm[o] = make_float4(aS[0], aS[1], aS[2], aS[3]);
}

// ---------------- q_chunk[b,h,d] via C/S (exact fp32) ----------------
__global__ __launch_bounds__(256) void qchunk_kernel(const float* __restrict__ Wq,
                                                     const float* __restrict__ Cm,
                                                     const float* __restrict__ Sm,
                                                     float* __restrict__ qc) {
  int gid = blockIdx.x * 256 + threadIdx.x;
  int wid = gid >> 6, lane = gid & 63;
  int b = wid >> 11, rem = wid & 2047;
  int h = rem >> 7, d = rem & 127;
  const float* crow = Cm + ((size_t)b * DH_ + d) * D_;
  const float* srow = Sm + ((size_t)b * DH_ + d) * D_;
  const float* w1 = Wq + (size_t)(h * DH_ + d) * D_;
  int dp = (d < 64) ? d + 64 : d - 64;
  float sgn = (d < 64) ? -1.f : 1.f;
  const float* w2 = Wq + (size_t)(h * DH_ + dp) * D_;
  float a1 = 0.f, a2 = 0.f;
  for (int j = lane; j < D_; j += 64) { a1 += w1[j] * crow[j]; a2 += w2[j] * srow[j]; }
#pragma unroll
  for (int off = 1; off < 64; off <<= 1) { a1 += __shfl_xor(a1, off); a2 += __shfl_xor(a2, off); }
  if (lane == 0) qc[wid] = (a1 + sgn * a2) * (1.f / (float)T_);
}

// ---------------- z[b,h,j] = sum_d qc[b,h,d] * Wk[kvh*128+d][j]  (fp32 exact) ----------------
__global__ __launch_bounds__(256) void zk_kernel(const float* __restrict__ qc,
                                                 const float* __restrict__ Wk,
                                                 float* __restrict__ z) {
  int j = blockIdx.x * 256 + threadIdx.x;   // grid.x = D/256
  int h = blockIdx.y, b = blockIdx.z;
  int kvh = h >> 1;
  const float* qcl = qc + ((size_t)b * H_ + h) * DH_;
  const float* wb = Wk + (size_t)kvh * DH_ * D_ + j;
  float acc = 0.f;
#pragma unroll 8
  for (int d = 0; d < 128; ++d) acc += qcl[d] * wb[(size_t)d * D_];
  z[((size_t)b * H_ + h) * D_ + j] = acc;
}

// ---------------- sim[b,h,n] = kScale * z[b,h,:] . mem[b,n,:] ----------------
__global__ __launch_bounds__(256) void sim_kernel(const float* __restrict__ z,
                                                  const float* __restrict__ mem,
                                                  float* __restrict__ sim) {
  __shared__ float4 mL[16 * 512];   // 128 KB, XOR-swizzled rows
  int tid = threadIdx.x;
  int n0 = blockIdx.x * 16, b = blockIdx.y;
  const float4* mem4 = (const float4*)(mem + (size_t)b * NMEM * D_);
#pragma unroll
  for (int c = 0; c < 32; ++c) {
    int i = tid + c * 256;          // [0, 8192)
    int r = i >> 9, j4 = i & 511;
    mL[r * 512 + (j4 ^ (r & 7))] = mem4[(size_t)(n0 + r) * 512 + j4];
  }
  __syncthreads();
  int h = tid >> 4, n = tid & 15;
  const float4* zr = (const float4*)(z + ((size_t)b * H_ + h) * D_);
  float acc = 0.f;
  for (int j4 = 0; j4 < 512; ++j4) {
    float4 zz = zr[j4];
    float4 mm = mL[n * 512 + (j4 ^ (n & 7))];
    acc += zz.x * mm.x + zz.y * mm.y + zz.z * mm.z + zz.w * mm.w;
  }
  sim[((size_t)b * H_ + h) * NMEM + n0 + n] = acc * kScale;
}

// ---------------- top-8 per (b,h) (ties -> lowest index, matching lax.top_k) ----------------
__global__ __launch_bounds__(256) void topk_kernel(const float* __restrict__ sim,
                                                   int* __restrict__ idx) {
  __shared__ float sL[1024];
  __shared__ float rv[256];
  __shared__ int ri[256];
  int tid = threadIdx.x;
  int h = blockIdx.x, b = blockIdx.y;
  const float* sp = sim + ((size_t)b * H_ + h) * NMEM;
#pragma unroll
  for (int r = 0; r < 4; ++r) sL[tid + r * 256] = sp[tid + r * 256];
  __syncthreads();
  for (int kk = 0; kk < 8; ++kk) {
    float bv = -INFINITY; int bi = 0x7fffffff;
#pragma unroll
    for (int r = 0; r < 4; ++r) {
      int i = tid + r * 256;
      float v = sL[i];
      if (v > bv || (v == bv && i < bi)) { bv = v; bi = i; }
    }
    rv[tid] = bv; ri[tid] = bi;
    __syncthreads();
    for (int s = 128; s > 0; s >>= 1) {
      if (tid < s) {
        float v2 = rv[tid + s]; int i2 = ri[tid + s];
        if (v2 > rv[tid] || (v2 == rv[tid] && i2 < ri[tid])) { rv[tid] = v2; ri[tid] = i2; }
      }
      __syncthreads();
    }
    if (tid == 0) { idx[((size_t)b * H_ + h) * KSEL + kk] = ri[0]; sL[ri[0]] = -INFINITY; }
    __syncthreads();
  }
}

// ---------------- gather-project: k_sh / v_sh = W_head @ mem[selected] (fp32, coalesced) ----------------
__global__ __launch_bounds__(256) void gproj_kernel(const int* __restrict__ idx,
                                                    const float* __restrict__ Wk,
                                                    const float* __restrict__ Wv,
                                                    const float* __restrict__ mem,
                                                    float* __restrict__ kshp,
                                                    float* __restrict__ vshp) {
  __shared__ __align__(16) float mL[8][2048];   // 64 KB: the 8 selected rows
  int tid = threadIdx.x;
  int half = blockIdx.x, h = blockIdx.y, b = blockIdx.z;
  int kvh = h >> 1;
  const int* sel = idx + ((size_t)b * H_ + h) * KSEL;
#pragma unroll
  for (int c = 0; c < 16; ++c) {
    int i = tid + c * 256;          // [0, 4096) float4 units
    int r = i >> 9, j4 = i & 511;
    *(float4*)&mL[r][j4 * 4] =
        *(const float4*)(mem + ((size_t)b * NMEM + sel[r]) * D_ + (size_t)j4 * 4);
  }
  __syncthreads();
  const float* W = half ? Wv : Wk;
  int wv = tid >> 6, lane = tid & 63;
  float* outp = (half ? vshp : kshp) + ((size_t)b * H_ + h) * KSEL * DH_;
  for (int d = wv; d < DH_; d += 4) {
    const float4* wr = (const float4*)(W + (size_t)(kvh * DH_ + d) * D_);
    float acc[8] = {0.f,0.f,0.f,0.f,0.f,0.f,0.f,0.f};
#pragma unroll
    for (int c = 0; c < 8; ++c) {
      float4 w4 = wr[lane + c * 64];
      int j = (lane + c * 64) * 4;
#pragma unroll
      for (int kk = 0; kk < 8; ++kk) {
        float4 m4 = *(const float4*)&mL[kk][j];
        acc[kk] += w4.x * m4.x + w4.y * m4.y + w4.z * m4.z + w4.w * m4.w;
      }
    }
#pragma unroll
    for (int kk = 0; kk < 8; ++kk)
#pragma unroll
      for (int off = 1; off < 64; off <<= 1) acc[kk] += __shfl_xor(acc[kk], off);
#pragma unroll
    for (int kk = 0; kk < 8; ++kk)
      if (lane == kk) outp[kk * DH_ + d] = acc[kk];
  }
}

// ---------------- memory-branch attention: o_mem (bf16) -> ws ----------------
__global__ __launch_bounds__(256) void memattn_kernel(const unsigned short* __restrict__ qbf,
                                                      const float* __restrict__ ksh,
                                                      const float* __restrict__ vsh,
                                                      unsigned short* __restrict__ omem) {
  __shared__ float kl[8][128];
  __shared__ float vl[8][128];
  int tid = threadIdx.x;
  int b = blockIdx.z, h = blockIdx.y, t = blockIdx.x * 256 + tid;
  const float* ks = ksh + ((size_t)b * H_ + h) * KSEL * DH_;
  const float* vs = vsh + ((size_t)b * H_ + h) * KSEL * DH_;
#pragma unroll
  for (int r = 0; r < 4; ++r) {
    int i = tid + r * 256;
    ((float*)kl)[i] = ks[i];
    ((float*)vl)[i] = vs[i];
  }
  __syncthreads();
  float sc[8] = {0.f,0.f,0.f,0.f,0.f,0.f,0.f,0.f};
  const unsigned short* qr = qbf + (size_t)(b * T_ + t) * D_ + h * DH_;
  for (int c = 0; c < 4; ++c) {
    const s16x8* qp = (const s16x8*)(qr + c * 32);
#pragma unroll
    for (int u = 0; u < 4; ++u) {
      s16x8 q8 = qp[u];
#pragma unroll
      for (int e = 0; e < 8; ++e) {
        float qv = bf2f((unsigned short)q8[e]);
        int d = c * 32 + u * 8 + e;
#pragma unroll
        for (int kk = 0; kk < 8; ++kk) sc[kk] += qv * kl[kk][d];
      }
    }
  }
  float sm[8], mx = -INFINITY;
#pragma unroll
  for (int kk = 0; kk < 8; ++kk) { sm[kk] = sc[kk] * kScale; mx = fmaxf(mx, sm[kk]); }
  float sum = 0.f;
#pragma unroll
  for (int kk = 0; kk < 8; ++kk) { sm[kk] = __expf(sm[kk] - mx); sum += sm[kk]; }
  float inv = 1.f / sum;
#pragma unroll
  for (int kk = 0; kk < 8; ++kk) sm[kk] *= inv;
  unsigned short* orow = omem + (size_t)(b * T_ + t) * D_ + h * DH_;
  for (int d = 0; d < 128; d += 4) {
    float o0 = 0.f, o1 = 0.f, o2 = 0.f, o3 = 0.f;
#pragma unroll
    for (int kk = 0; kk < 8; ++kk) {
      float w = sm[kk];
      o0 += w * vl[kk][d + 0];
      o1 += w * vl[kk][d + 1];
      o2 += w * vl[kk][d + 2];
      o3 += w * vl[kk][d + 3];
    }
    uint2 pk;
    pk.x = (unsigned)f2bf(o0) | ((unsigned)f2bf(o1) << 16);
    pk.y = (unsigned)f2bf(o2) | ((unsigned)f2bf(o3) << 16);
    *(uint2*)(orow + d) = pk;
  }
}

// ---------------- gate: g = sigmoid(hs . Wg + bg) ----------------
__global__ __launch_bounds__(256) void gate_kernel(const float* __restrict__ hs,
                                                   const float* __restrict__ Wg,
                                                   const float* __restrict__ bg,
                                                   float* __restrict__ g) {
  int gid = blockIdx.x * 256 + threadIdx.x;
  int row = gid >> 6, lane = gid & 63;
  const float4* hr = (const float4*)(hs + (size_t)row * D_);
  const float4* wg4 = (const float4*)Wg;
  float acc = 0.f;
#pragma unroll
  for (int it = 0; it < 8; ++it) {
    float4 hv = hr[lane + it * 64], wv = wg4[lane + it * 64];
    acc += hv.x * wv.x + hv.y * wv.y + hv.z * wv.z + hv.w * wv.w;
  }
#pragma unroll
  for (int off = 1; off < 64; off <<= 1) acc += __shfl_xor(acc, off);
  if (lane == 0) g[row] = 1.f / (1.f + __expf(-(acc + bg[0])));
}

// ---------------- local sliding-window attention (flash, per-wave 16 rows) ----------------
__global__ __launch_bounds__(256) void localattn_kernel(const unsigned short* __restrict__ qbf,
                                                        const unsigned short* __restrict__ kbf,
                                                        const unsigned short* __restrict__ vbf,
                                                        unsigned short* __restrict__ olocal) {
  __shared__ __align__(16) unsigned short pl[4][16][40];
  const int tid = threadIdx.x;
  const int w = tid >> 6, lane = tid & 63;
  const int tb = blockIdx.x * 64;
  const int h = blockIdx.y, b = blockIdx.z;
  const int kvh = h >> 1;
  const int t0 = tb + w * 16;
  const int l15 = lane & 15, lg = lane >> 4;

  s16x8 qf[4];
  {
    const unsigned short* qb = qbf + ((size_t)(b * T_ + t0 + l15) * D_) + h * DH_ + lg * 8;
#pragma unroll
    for (int kb = 0; kb < 4; ++kb) qf[kb] = *(const s16x8*)(qb + kb * 32);
  }
  f32x4 of[8];
#pragma unroll
  for (int nb = 0; nb < 8; ++nb) of[nb] = fzero4();
  float m_r[4] = {-INFINITY, -INFINITY, -INFINITY, -INFINITY};
  float l_r[4] = {0.f, 0.f, 0.f, 0.f};

  int sstart = t0 - (WWIN - 1);
  if (sstart < 0) sstart = 0;
  sstart &= ~31;
  for (int s0 = sstart; s0 <= t0 + 15; s0 += 32) {
    f32x4 sc[2];
    sc[0] = fzero4(); sc[1] = fzero4();
    const unsigned short* kb0 = kbf + ((size_t)(b * T_ + s0 + l15) * (KV_ * DH_)) + kvh * DH_ + lg * 8;
#pragma unroll
    for (int cb = 0; cb < 2; ++cb) {
#pragma unroll
      for (int kb = 0; kb < 4; ++kb) {
        s16x8 kf = *(const s16x8*)(kb0 + (size_t)cb * 16 * (KV_ * DH_) + kb * 32);
        sc[cb] = __builtin_amdgcn_mfma_f32_16x16x32_bf16(qf[kb], kf, sc[cb], 0, 0, 0);
      }
    }
    float pv[2][4];
#pragma unroll
    for (int j = 0; j < 4; ++j) {
      int t = t0 + lg * 4 + j;
      int s_a = s0 + l15, s_b = s_a + 16;
      float va = sc[0][j] * kScale;
      float vb = sc[1][j] * kScale;
      va = (s_a <= t && s_a + (WWIN - 1) >= t) ? va : -INFINITY;
      vb = (s_b <= t && s_b + (WWIN - 1) >= t) ? vb : -INFINITY;
      float mx = fmaxf(va, vb);
#pragma unroll
      for (int off = 1; off < 16; off <<= 1) mx = fmaxf(mx, __shfl_xor(mx, off));
      float mn = fmaxf(m_r[j], mx);
      float alpha, pa, pb;
      if (mn == -INFINITY) { alpha = 1.f; pa = 0.f; pb = 0.f; }
      else {
        alpha = __expf(m_r[j] - mn);
        pa = __expf(va - mn);
        pb = __expf(vb - mn);
      }
      m_r[j] = mn;
      float rs = pa + pb;
#pragma unroll
      for (int off = 1; off < 16; off <<= 1) rs += __shfl_xor(rs, off);
      l_r[j] = l_r[j] * alpha + rs;
#pragma unroll
      for (int nb = 0; nb < 8; ++nb) of[nb][j] *= alpha;
      pv[0][j] = pa; pv[1][j] = pb;
    }
#pragma unroll
    for (int cb = 0; cb < 2; ++cb)
#pragma unroll
      for (int j = 0; j < 4; ++j)
        pl[w][lg * 4 + j][cb * 16 + l15] = f2bf(pv[cb][j]);
    asm volatile("s_waitcnt lgkmcnt(0)" ::: "memory");
    __builtin_amdgcn_sched_barrier(0);
    s16x8 pa8 = *(const s16x8*)&pl[w][l15][lg * 8];
    const unsigned short* vb0 = vbf + ((size_t)(b * T_ + s0 + lg * 8) * (KV_ * DH_)) + kvh * DH_ + l15;
#pragma unroll
    for (int nb = 0; nb < 8; ++nb) {
      s16x8 vf;
#pragma unroll
      for (int jj = 0; jj < 8; ++jj) vf[jj] = (short)vb0[(size_t)jj * (KV_ * DH_) + nb * 16];
      of[nb] = __builtin_amdgcn_mfma_f32_16x16x32_bf16(pa8, vf, of[nb], 0, 0, 0);
    }
  }
  float inv[4];
#pragma unroll
  for (int j = 0; j < 4; ++j) inv[j] = 1.f / l_r[j];
#pragma unroll
  for (int nb = 0; nb < 8; ++nb)
#pragma unroll
    for (int j = 0; j < 4; ++j) {
      int t = t0 + lg * 4 + j;
      olocal[(size_t)(b * T_ + t) * D_ + h * DH_ + nb * 16 + l15] = f2bf(of[nb][j] * inv[j]);
    }
}

// ---------------- host launcher ----------------
extern "C" void kernel_launch(void* const* d_in, const int* in_sizes, int n_in,
                              void* d_out, int out_size, void* d_ws, size_t ws_size,
                              hipStream_t stream) {
  const float* hs   = (const float*)d_in[0];
  const float* cosp = (const float*)d_in[1];
  const float* sinp = (const float*)d_in[2];
  const float* mem  = (const float*)d_in[3];
  const float* Wq   = (const float*)d_in[4];
  const float* Wk   = (const float*)d_in[5];
  const float* Wv   = (const float*)d_in[6];
  const float* Wo   = (const float*)d_in[7];
  const float* Wg   = (const float*)d_in[8];
  const float* bg   = (const float*)d_in[9];
  float* out = (float*)d_out;

  char* p = (char*)d_ws;
  auto alloc = [&](size_t bytes) { char* r = p; p += (bytes + 255) & ~(size_t)255; return r; };
  // small buffers FIRST (overflow safety), then big buffers. Total ~84.7 MB.
  float* qc     = (float*)alloc((size_t)B_ * H_ * DH_ * 4);
  float* ksh    = (float*)alloc((size_t)B_ * H_ * KSEL * DH_ * 4);
  float* vsh    = (float*)alloc((size_t)B_ * H_ * KSEL * DH_ * 4);
  float* gbuf   = (float*)alloc((size_t)BT * 4);
  float* zbuf   = (float*)alloc((size_t)B_ * H_ * D_ * 4);
  float* simbuf = (float*)alloc((size_t)B_ * H_ * NMEM * 4);
  int*   idxbuf = (int*)alloc((size_t)B_ * H_ * KSEL * 4);
  unsigned short* hs_bf = (unsigned short*)alloc((size_t)BT * D_ * 2);        // -> o_mem bf16
  unsigned short* q_raw = (unsigned short*)alloc((size_t)BT * D_ * 2);        // -> o_local
  unsigned short* q_bf  = (unsigned short*)alloc((size_t)BT * D_ * 2);
  unsigned short* k_raw = (unsigned short*)alloc((size_t)BT * KV_ * DH_ * 2); // -> Cm/Sm
  unsigned short* k_bf  = (unsigned short*)alloc((size_t)BT * KV_ * DH_ * 2);
  unsigned short* v_bf  = (unsigned short*)alloc((size_t)BT * KV_ * DH_ * 2);
  unsigned short* wbig  = (unsigned short*)alloc((size_t)D_ * D_ * 2);        // Wq then Wo
  unsigned short* wkv   = (unsigned short*)alloc((size_t)KV_ * DH_ * D_ * 2); // Wk then Wv

  float* Cm = (float*)k_raw;                       // after rope-k, k_raw is dead
  float* Sm = Cm + (size_t)B_ * DH_ * D_;
  unsigned short* o_local = q_raw;                 // after rope-q, q_raw is dead
  unsigned short* omem_bf = hs_bf;                 // after v-gemm, hs_bf is dead

  // 1) conversions + projections (bf16 MFMA); weight buffers reused sequentially
  conv_kernel<<<(BT * D_ / 4 + 255) / 256, 256, 0, stream>>>(hs, hs_bf, BT * D_);
  conv_kernel<<<(D_ * D_ / 4 + 255) / 256, 256, 0, stream>>>(Wq, wbig, D_ * D_);
  gemm_bt<0><<<dim3(D_ / 128, BT / 128), 256, 0, stream>>>(hs_bf, wbig, D_, D_, q_raw, nullptr, nullptr, nullptr);
  conv_kernel<<<(KV_ * DH_ * D_ / 4 + 255) / 256, 256, 0, stream>>>(Wk, wkv, KV_ * DH_ * D_);
  gemm_bt<0><<<dim3(KV_ * DH_ / 128, BT / 128), 256, 0, stream>>>(hs_bf, wkv, KV_ * DH_, D_, k_raw, nullptr, nullptr, nullptr);
  conv_kernel<<<(KV_ * DH_ * D_ / 4 + 255) / 256, 256, 0, stream>>>(Wv, wkv, KV_ * DH_ * D_);
  gemm_bt<0><<<dim3(KV_ * DH_ / 128, BT / 128), 256, 0, stream>>>(hs_bf, wkv, KV_ * DH_, D_, v_bf, nullptr, nullptr, nullptr);

  // 2) RoPE
  rope_kernel<<<BT * D_ / 256, 256, 0, stream>>>(q_raw, q_bf, cosp, sinp, 11, BT * D_);
  rope_kernel<<<BT * KV_ * DH_ / 256, 256, 0, stream>>>(k_raw, k_bf, cosp, sinp, 10, BT * KV_ * DH_);

  // 3) exact-fp32 selection path (parallelized)
  cs_kernel<<<dim3(D_ / 64, DH_ / 16, B_), 256, 0, stream>>>(hs, cosp, sinp, Cm, Sm);
  qchunk_kernel<<<(B_ * H_ * DH_) / 4, 256, 0, stream>>>(Wq, Cm, Sm, qc);
  zk_kernel<<<dim3(D_ / 256, H_, B_), 256, 0, stream>>>(qc, Wk, zbuf);
  sim_kernel<<<dim3(NMEM / 16, B_), 256, 0, stream>>>(zbuf, mem, simbuf);
  topk_kernel<<<dim3(H_, B_), 256, 0, stream>>>(simbuf, idxbuf);
  gproj_kernel<<<dim3(2, H_, B_), 256, 0, stream>>>(idxbuf, Wk, Wv, mem, ksh, vsh);

  // 4) memory-branch attention -> o_mem bf16 (reuses hs_bf)
  memattn_kernel<<<dim3(T_ / 256, H_, B_), 256, 0, stream>>>(q_bf, ksh, vsh, omem_bf);

  // 5) gate
  gate_kernel<<<BT / 4, 256, 0, stream>>>(hs, Wg, bg, gbuf);

  // 6) local sliding-window attention
  localattn_kernel<<<dim3(T_ / 64, H_, B_), 256, 0, stream>>>(q_bf, k_bf, v_bf, o_local);

  // 7) Wo projection + final combine (d_out pure write)
  conv_kernel<<<(D_ * D_ / 4 + 255) / 256, 256, 0, stream>>>(Wo, wbig, D_ * D_);
  gemm_bt<1><<<dim3(D_ / 128, BT / 128), 256, 0, stream>>>(o_local, wbig, D_, D_, nullptr, gbuf, omem_bf, out);
}

// Round 4
// 619.214 us; speedup vs baseline: 1.6359x; 1.1006x over previous
//
#include <hip/hip_runtime.h>
#include <stdint.h>

#define B_   2
#define T_   2048
#define D_   2048
#define H_   16
#define KV_  8
#define DH_  128
#define NMEM 1024
#define WWIN 256
#define KSEL 8
#define BT   (B_*T_)
#define KVSTR 2048   // merged KV row stride (elements)

__constant__ const float kScale = 0.08838834764831845f; // DH^-0.5

typedef __attribute__((ext_vector_type(8))) short s16x8;
typedef __attribute__((ext_vector_type(4))) float f32x4;

__device__ inline unsigned short f2bf(float f) {
  union { float f; unsigned int u; } c; c.f = f;
  unsigned int u = c.u;
  unsigned int r = u + 0x7fffu + ((u >> 16) & 1u);
  return (unsigned short)(r >> 16);
}
__device__ inline float bf2f(unsigned short v) {
  union { unsigned int u; float f; } c; c.u = ((unsigned int)v) << 16;
  return c.f;
}
__device__ inline f32x4 fzero4() { f32x4 v; v[0]=0.f; v[1]=0.f; v[2]=0.f; v[3]=0.f; return v; }

// ---------------- fp32 -> bf16 conversion (float4 wide) ----------------
__global__ __launch_bounds__(256) void conv_kernel(const float* __restrict__ src,
                                                   unsigned short* __restrict__ dst, int n) {
  int i = blockIdx.x * 256 + threadIdx.x;
  if (i * 4 >= n) return;
  float4 v = ((const float4*)src)[i];
  uint2 o;
  o.x = (unsigned)f2bf(v.x) | ((unsigned)f2bf(v.y) << 16);
  o.y = (unsigned)f2bf(v.z) | ((unsigned)f2bf(v.w) << 16);
  ((uint2*)dst)[i] = o;
}

// ---------------- bf16 GEMM: C[M,N] = A[M,K] @ B[N,K]^T ----------------
// MODE 0: write bf16 C.
// MODE 1: dout = g[row]*acc + (1-g[row])*bf2f(omem[o])   (d_out pure write)
template<int MODE>
__global__ __launch_bounds__(256) void gemm_bt(const unsigned short* __restrict__ A,
                                               const unsigned short* __restrict__ Bw,
                                               int N, int K,
                                               unsigned short* __restrict__ Cb,
                                               const float* __restrict__ g,
                                               const unsigned short* __restrict__ omem,
                                               float* __restrict__ dout) {
  __shared__ __align__(16) unsigned short sA[128 * 32];
  __shared__ __align__(16) unsigned short sB[128 * 32];
  const int tid = threadIdx.x;
  const int wv = tid >> 6, lane = tid & 63;
  // XCD-aware bijective swizzle (nwg % 8 == 0 for all our launches)
  const int gx = gridDim.x;
  const int nwg = gx * gridDim.y;
  const int flat = blockIdx.y * gx + blockIdx.x;
  const int chunk = nwg >> 3;
  const int wg = (flat & 7) * chunk + (flat >> 3);
  const int bx = wg % gx, by = wg / gx;
  const int m0 = by * 128, n0 = bx * 128;
  const int wr = wv >> 1, wc = wv & 1;
  const int l15 = lane & 15, lg = lane >> 4;
  const int rowA = tid >> 2;
  const int colB = (tid & 3) * 16; // bytes
  f32x4 acc[4][4];
#pragma unroll
  for (int mi = 0; mi < 4; ++mi)
#pragma unroll
    for (int ni = 0; ni < 4; ++ni) acc[mi][ni] = fzero4();

  char* sAc = (char*)sA;
  char* sBc = (char*)sB;
  for (int k0 = 0; k0 < K; k0 += 32) {
#pragma unroll
    for (int e = 0; e < 2; ++e) {
      const char* ga = (const char*)(A + ((size_t)(m0 + rowA + e * 64) * K + k0)) + colB;
      __builtin_amdgcn_global_load_lds((const __attribute__((address_space(1))) void*)ga,
          (__attribute__((address_space(3))) void*)(sAc + e * 4096 + wv * 1024), 16, 0, 0);
      const char* gb = (const char*)(Bw + ((size_t)(n0 + rowA + e * 64) * K + k0)) + colB;
      __builtin_amdgcn_global_load_lds((const __attribute__((address_space(1))) void*)gb,
          (__attribute__((address_space(3))) void*)(sBc + e * 4096 + wv * 1024), 16, 0, 0);
    }
    __syncthreads();
    s16x8 af[4], bf_[4];
#pragma unroll
    for (int mi = 0; mi < 4; ++mi)
      af[mi] = *(const s16x8*)&sA[(wr * 64 + mi * 16 + l15) * 32 + lg * 8];
#pragma unroll
    for (int ni = 0; ni < 4; ++ni)
      bf_[ni] = *(const s16x8*)&sB[(wc * 64 + ni * 16 + l15) * 32 + lg * 8];
#pragma unroll
    for (int mi = 0; mi < 4; ++mi)
#pragma unroll
      for (int ni = 0; ni < 4; ++ni)
        acc[mi][ni] = __builtin_amdgcn_mfma_f32_16x16x32_bf16(af[mi], bf_[ni], acc[mi][ni], 0, 0, 0);
    __syncthreads();
  }
#pragma unroll
  for (int mi = 0; mi < 4; ++mi)
#pragma unroll
    for (int ni = 0; ni < 4; ++ni)
#pragma unroll
      for (int j = 0; j < 4; ++j) {
        int row_g = m0 + wr * 64 + mi * 16 + lg * 4 + j;
        int col_g = n0 + wc * 64 + ni * 16 + l15;
        float v = acc[mi][ni][j];
        if constexpr (MODE == 0) {
          Cb[(size_t)row_g * N + col_g] = f2bf(v);
        } else {
          float gv = g[row_g];
          size_t o = (size_t)row_g * N + col_g;
          float om = bf2f(omem[o]);
          dout[o] = gv * v + (1.f - gv) * om;
        }
      }
}

// ---------------- RoPE (bf16 in/out; src row-stride parametrized) ----------------
__global__ __launch_bounds__(256) void rope_kernel(const unsigned short* __restrict__ src,
                                                   unsigned short* __restrict__ dst,
                                                   const float* __restrict__ cosp,
                                                   const float* __restrict__ sinp,
                                                   int logw, int sstride, int total) {
  int i = blockIdx.x * 256 + threadIdx.x;
  if (i >= total) return;
  int width = 1 << logw;
  int row = i >> logw;
  int c = i & (width - 1);
  int d = c & 127;
  int b = row >> 11, t = row & 2047;
  float cv = cosp[((size_t)b * T_ + t) * DH_ + d];
  float sv = sinp[((size_t)b * T_ + t) * DH_ + d];
  size_t si = (size_t)row * sstride + c;
  float x = bf2f(src[si]);
  float xr = (d < 64) ? -bf2f(src[si + 64]) : bf2f(src[si - 64]);
  dst[i] = f2bf(x * cv + xr * sv);
}

// ---------------- C/S partials: Cp[sp,b,d,j] = sum_{t in sp} cos[b,t,d]*hs[b,t,j] ----------------
// grid (D/128, 32/32*? , B*4): x = j-tile(128), y = d-tile(32), z = b*4+sp
__global__ __launch_bounds__(256) void cs_kernel(const float* __restrict__ hs,
                                                 const float* __restrict__ cosp,
                                                 const float* __restrict__ sinp,
                                                 float* __restrict__ Cp, float* __restrict__ Sp) {
  __shared__ __align__(16) float hsL[32][128];
  __shared__ __align__(16) float csL[32][32];
  __shared__ __align__(16) float snL[32][32];
  const int tid = threadIdx.x;
  const int j0 = blockIdx.x * 128, d0 = blockIdx.y * 32;
  const int b = blockIdx.z >> 2, sp = blockIdx.z & 3;
  const int dq = (tid & 7) * 4;     // d offset in [0,32)
  const int jq = (tid >> 3) * 4;    // j offset in [0,128)
  float4 aC[4], aS[4];
#pragma unroll
  for (int a = 0; a < 4; ++a) {
    aC[a] = make_float4(0.f, 0.f, 0.f, 0.f);
    aS[a] = make_float4(0.f, 0.f, 0.f, 0.f);
  }
  const int csrow = tid >> 3, csc4 = tid & 7;
  for (int tile = 0; tile < 16; ++tile) {
    int t0 = sp * 512 + tile * 32;
    const float4* hs4 = (const float4*)(hs + ((size_t)b * T_ + t0) * D_ + j0);
#pragma unroll
    for (int r = 0; r < 4; ++r) {
      int i = tid + r * 256;
      int row = i >> 5, c4 = i & 31;
      *(float4*)&hsL[row][c4 * 4] = hs4[(size_t)row * (D_ / 4) + c4];
    }
    const float4* cp4 = (const float4*)(cosp + ((size_t)b * T_ + t0) * DH_ + d0);
    const float4* sp4 = (const float4*)(sinp + ((size_t)b * T_ + t0) * DH_ + d0);
    *(float4*)&csL[csrow][csc4 * 4] = cp4[(size_t)csrow * (DH_ / 4) + csc4];
    *(float4*)&snL[csrow][csc4 * 4] = sp4[(size_t)csrow * (DH_ / 4) + csc4];
    __syncthreads();
#pragma unroll 8
    for (int tt = 0; tt < 32; ++tt) {
      float4 cv = *(const float4*)&csL[tt][dq];
      float4 sv = *(const float4*)&snL[tt][dq];
      float4 hv = *(const float4*)&hsL[tt][jq];
      float ca[4] = {cv.x, cv.y, cv.z, cv.w};
      float sa[4] = {sv.x, sv.y, sv.z, sv.w};
#pragma unroll
      for (int a = 0; a < 4; ++a) {
        aC[a].x += ca[a] * hv.x; aC[a].y += ca[a] * hv.y;
        aC[a].z += ca[a] * hv.z; aC[a].w += ca[a] * hv.w;
        aS[a].x += sa[a] * hv.x; aS[a].y += sa[a] * hv.y;
        aS[a].z += sa[a] * hv.z; aS[a].w += sa[a] * hv.w;
      }
    }
    __syncthreads();
  }
#pragma unroll
  for (int a = 0; a < 4; ++a) {
    size_t o = ((size_t)(sp * B_ + b) * DH_ + d0 + dq + a) * D_ + j0 + jq;
    *(float4*)&Cp[o] = aC[a];
    *(float4*)&Sp[o] = aS[a];
  }
}

// ---------------- q_chunk[b,h,d] from 4 C/S partials (exact fp32) ----------------
__global__ __launch_bounds__(256) void qchunk_kernel(const float* __restrict__ Wq,
                                                     const float* __restrict__ Cp,
                                                     const float* __restrict__ Sp,
                                                     float* __restrict__ qc) {
  int gid = blockIdx.x * 256 + threadIdx.x;
  int wid = gid >> 6, lane = gid & 63;
  int b = wid >> 11, rem = wid & 2047;
  int h = rem >> 7, d = rem & 127;
  const float* w1 = Wq + (size_t)(h * DH_ + d) * D_;
  int dp = (d < 64) ? d + 64 : d - 64;
  float sgn = (d < 64) ? -1.f : 1.f;
  const float* w2 = Wq + (size_t)(h * DH_ + dp) * D_;
  float a1 = 0.f, a2 = 0.f;
#pragma unroll
  for (int p = 0; p < 4; ++p) {
    const float* crow = Cp + ((size_t)(p * B_ + b) * DH_ + d) * D_;
    const float* srow = Sp + ((size_t)(p * B_ + b) * DH_ + d) * D_;
    for (int j = lane; j < D_; j += 64) { a1 += w1[j] * crow[j]; a2 += w2[j] * srow[j]; }
  }
#pragma unroll
  for (int off = 1; off < 64; off <<= 1) { a1 += __shfl_xor(a1, off); a2 += __shfl_xor(a2, off); }
  if (lane == 0) qc[wid] = (a1 + sgn * a2) * (1.f / (float)T_);
}

// ---------------- z[b,h,j] = sum_d qc[b,h,d] * Wk[kvh*128+d][j]  (fp32 exact) ----------------
__global__ __launch_bounds__(256) void zk_kernel(const float* __restrict__ qc,
                                                 const float* __restrict__ Wk,
                                                 float* __restrict__ z) {
  int j = blockIdx.x * 256 + threadIdx.x;   // grid.x = D/256
  int h = blockIdx.y, b = blockIdx.z;
  int kvh = h >> 1;
  const float* qcl = qc + ((size_t)b * H_ + h) * DH_;
  const float* wb = Wk + (size_t)kvh * DH_ * D_ + j;
  float acc = 0.f;
#pragma unroll 8
  for (int d = 0; d < 128; ++d) acc += qcl[d] * wb[(size_t)d * D_];
  z[((size_t)b * H_ + h) * D_ + j] = acc;
}

// ---------------- sim[b,h,n] = kScale * z[b,h,:] . mem[b,n,:] ----------------
__global__ __launch_bounds__(256) void sim_kernel(const float* __restrict__ z,
                                                  const float* __restrict__ mem,
                                                  float* __restrict__ sim) {
  __shared__ float4 mL[16 * 512];   // 128 KB, XOR-swizzled rows
  int tid = threadIdx.x;
  int n0 = blockIdx.x * 16, b = blockIdx.y;
  const float4* mem4 = (const float4*)(mem + (size_t)b * NMEM * D_);
#pragma unroll
  for (int c = 0; c < 32; ++c) {
    int i = tid + c * 256;          // [0, 8192)
    int r = i >> 9, j4 = i & 511;
    mL[r * 512 + (j4 ^ (r & 7))] = mem4[(size_t)(n0 + r) * 512 + j4];
  }
  __syncthreads();
  int h = tid >> 4, n = tid & 15;
  const float4* zr = (const float4*)(z + ((size_t)b * H_ + h) * D_);
  float acc = 0.f;
  for (int j4 = 0; j4 < 512; ++j4) {
    float4 zz = zr[j4];
    float4 mm = mL[n * 512 + (j4 ^ (n & 7))];
    acc += zz.x * mm.x + zz.y * mm.y + zz.z * mm.z + zz.w * mm.w;
  }
  sim[((size_t)b * H_ + h) * NMEM + n0 + n] = acc * kScale;
}

// ---------------- top-8 per (b,h) (ties -> lowest index, matching lax.top_k) ----------------
__global__ __launch_bounds__(256) void topk_kernel(const float* __restrict__ sim,
                                                   int* __restrict__ idx) {
  __shared__ float sL[1024];
  __shared__ float rv[256];
  __shared__ int ri[256];
  int tid = threadIdx.x;
  int h = blockIdx.x, b = blockIdx.y;
  const float* sp = sim + ((size_t)b * H_ + h) * NMEM;
#pragma unroll
  for (int r = 0; r < 4; ++r) sL[tid + r * 256] = sp[tid + r * 256];
  __syncthreads();
  for (int kk = 0; kk < 8; ++kk) {
    float bv = -INFINITY; int bi = 0x7fffffff;
#pragma unroll
    for (int r = 0; r < 4; ++r) {
      int i = tid + r * 256;
      float v = sL[i];
      if (v > bv || (v == bv && i < bi)) { bv = v; bi = i; }
    }
    rv[tid] = bv; ri[tid] = bi;
    __syncthreads();
    for (int s = 128; s > 0; s >>= 1) {
      if (tid < s) {
        float v2 = rv[tid + s]; int i2 = ri[tid + s];
        if (v2 > rv[tid] || (v2 == rv[tid] && i2 < ri[tid])) { rv[tid] = v2; ri[tid] = i2; }
      }
      __syncthreads();
    }
    if (tid == 0) { idx[((size_t)b * H_ + h) * KSEL + kk] = ri[0]; sL[ri[0]] = -INFINITY; }
    __syncthreads();
  }
}

// ---------------- gather-project: k_sh / v_sh = W_head @ mem[selected] (fp32, coalesced) ----------------
__global__ __launch_bounds__(256) void gproj_kernel(const int* __restrict__ idx,
                                                    const float* __restrict__ Wk,
                                                    const float* __restrict__ Wv,
                                                    const float* __restrict__ mem,
                                                    float* __restrict__ kshp,
                                                    float* __restrict__ vshp) {
  __shared__ __align__(16) float mL[8][2048];   // 64 KB: the 8 selected rows
  int tid = threadIdx.x;
  int half = blockIdx.x, h = blockIdx.y, b = blockIdx.z;
  int kvh = h >> 1;
  const int* sel = idx + ((size_t)b * H_ + h) * KSEL;
#pragma unroll
  for (int c = 0; c < 16; ++c) {
    int i = tid + c * 256;          // [0, 4096) float4 units
    int r = i >> 9, j4 = i & 511;
    *(float4*)&mL[r][j4 * 4] =
        *(const float4*)(mem + ((size_t)b * NMEM + sel[r]) * D_ + (size_t)j4 * 4);
  }
  __syncthreads();
  const float* W = half ? Wv : Wk;
  int wv = tid >> 6, lane = tid & 63;
  float* outp = (half ? vshp : kshp) + ((size_t)b * H_ + h) * KSEL * DH_;
  for (int d = wv; d < DH_; d += 4) {
    const float4* wr = (const float4*)(W + (size_t)(kvh * DH_ + d) * D_);
    float acc[8] = {0.f,0.f,0.f,0.f,0.f,0.f,0.f,0.f};
#pragma unroll
    for (int c = 0; c < 8; ++c) {
      float4 w4 = wr[lane + c * 64];
      int j = (lane + c * 64) * 4;
#pragma unroll
      for (int kk = 0; kk < 8; ++kk) {
        float4 m4 = *(const float4*)&mL[kk][j];
        acc[kk] += w4.x * m4.x + w4.y * m4.y + w4.z * m4.z + w4.w * m4.w;
      }
    }
#pragma unroll
    for (int kk = 0; kk < 8; ++kk)
#pragma unroll
      for (int off = 1; off < 64; off <<= 1) acc[kk] += __shfl_xor(acc[kk], off);
#pragma unroll
    for (int kk = 0; kk < 8; ++kk)
      if (lane == kk) outp[kk * DH_ + d] = acc[kk];
  }
}

// ---------------- memory-branch attention: o_mem (bf16) -> ws ----------------
__global__ __launch_bounds__(256) void memattn_kernel(const unsigned short* __restrict__ qbf,
                                                      const float* __restrict__ ksh,
                                                      const float* __restrict__ vsh,
                                                      unsigned short* __restrict__ omem) {
  __shared__ float kl[8][128];
  __shared__ float vl[8][128];
  int tid = threadIdx.x;
  int b = blockIdx.z, h = blockIdx.y, t = blockIdx.x * 256 + tid;
  const float* ks = ksh + ((size_t)b * H_ + h) * KSEL * DH_;
  const float* vs = vsh + ((size_t)b * H_ + h) * KSEL * DH_;
#pragma unroll
  for (int r = 0; r < 4; ++r) {
    int i = tid + r * 256;
    ((float*)kl)[i] = ks[i];
    ((float*)vl)[i] = vs[i];
  }
  __syncthreads();
  float sc[8] = {0.f,0.f,0.f,0.f,0.f,0.f,0.f,0.f};
  const unsigned short* qr = qbf + (size_t)(b * T_ + t) * D_ + h * DH_;
  for (int c = 0; c < 4; ++c) {
    const s16x8* qp = (const s16x8*)(qr + c * 32);
#pragma unroll
    for (int u = 0; u < 4; ++u) {
      s16x8 q8 = qp[u];
#pragma unroll
      for (int e = 0; e < 8; ++e) {
        float qv = bf2f((unsigned short)q8[e]);
        int d = c * 32 + u * 8 + e;
#pragma unroll
        for (int kk = 0; kk < 8; ++kk) sc[kk] += qv * kl[kk][d];
      }
    }
  }
  float sm[8], mx = -INFINITY;
#pragma unroll
  for (int kk = 0; kk < 8; ++kk) { sm[kk] = sc[kk] * kScale; mx = fmaxf(mx, sm[kk]); }
  float sum = 0.f;
#pragma unroll
  for (int kk = 0; kk < 8; ++kk) { sm[kk] = __expf(sm[kk] - mx); sum += sm[kk]; }
  float inv = 1.f / sum;
#pragma unroll
  for (int kk = 0; kk < 8; ++kk) sm[kk] *= inv;
  unsigned short* orow = omem + (size_t)(b * T_ + t) * D_ + h * DH_;
  for (int d = 0; d < 128; d += 4) {
    float o0 = 0.f, o1 = 0.f, o2 = 0.f, o3 = 0.f;
#pragma unroll
    for (int kk = 0; kk < 8; ++kk) {
      float w = sm[kk];
      o0 += w * vl[kk][d + 0];
      o1 += w * vl[kk][d + 1];
      o2 += w * vl[kk][d + 2];
      o3 += w * vl[kk][d + 3];
    }
    uint2 pk;
    pk.x = (unsigned)f2bf(o0) | ((unsigned)f2bf(o1) << 16);
    pk.y = (unsigned)f2bf(o2) | ((unsigned)f2bf(o3) << 16);
    *(uint2*)(orow + d) = pk;
  }
}

// ---------------- gate: g = sigmoid(hs . Wg + bg) ----------------
__global__ __launch_bounds__(256) void gate_kernel(const float* __restrict__ hs,
                                                   const float* __restrict__ Wg,
                                                   const float* __restrict__ bg,
                                                   float* __restrict__ g) {
  int gid = blockIdx.x * 256 + threadIdx.x;
  int row = gid >> 6, lane = gid & 63;
  const float4* hr = (const float4*)(hs + (size_t)row * D_);
  const float4* wg4 = (const float4*)Wg;
  float acc = 0.f;
#pragma unroll
  for (int it = 0; it < 8; ++it) {
    float4 hv = hr[lane + it * 64], wv = wg4[lane + it * 64];
    acc += hv.x * wv.x + hv.y * wv.y + hv.z * wv.z + hv.w * wv.w;
  }
#pragma unroll
  for (int off = 1; off < 64; off <<= 1) acc += __shfl_xor(acc, off);
  if (lane == 0) g[row] = 1.f / (1.f + __expf(-(acc + bg[0])));
}

// ---------------- local sliding-window attention (flash, per-wave 16 rows) ----------------
// kbf: roped K, row stride 1024. vbf: V columns inside merged KV buffer, row stride KVSTR.
__global__ __launch_bounds__(256) void localattn_kernel(const unsigned short* __restrict__ qbf,
                                                        const unsigned short* __restrict__ kbf,
                                                        const unsigned short* __restrict__ vbf,
                                                        unsigned short* __restrict__ olocal) {
  __shared__ __align__(16) unsigned short pl[4][16][40];
  const int tid = threadIdx.x;
  const int w = tid >> 6, lane = tid & 63;
  const int tb = blockIdx.x * 64;
  const int h = blockIdx.y, b = blockIdx.z;
  const int kvh = h >> 1;
  const int t0 = tb + w * 16;
  const int l15 = lane & 15, lg = lane >> 4;

  s16x8 qf[4];
  {
    const unsigned short* qb = qbf + ((size_t)(b * T_ + t0 + l15) * D_) + h * DH_ + lg * 8;
#pragma unroll
    for (int kb = 0; kb < 4; ++kb) qf[kb] = *(const s16x8*)(qb + kb * 32);
  }
  f32x4 of[8];
#pragma unroll
  for (int nb = 0; nb < 8; ++nb) of[nb] = fzero4();
  float m_r[4] = {-INFINITY, -INFINITY, -INFINITY, -INFINITY};
  float l_r[4] = {0.f, 0.f, 0.f, 0.f};

  int sstart = t0 - (WWIN - 1);
  if (sstart < 0) sstart = 0;
  sstart &= ~31;
  for (int s0 = sstart; s0 <= t0 + 15; s0 += 32) {
    f32x4 sc[2];
    sc[0] = fzero4(); sc[1] = fzero4();
    const unsigned short* kb0 = kbf + ((size_t)(b * T_ + s0 + l15) * (KV_ * DH_)) + kvh * DH_ + lg * 8;
#pragma unroll
    for (int cb = 0; cb < 2; ++cb) {
#pragma unroll
      for (int kb = 0; kb < 4; ++kb) {
        s16x8 kf = *(const s16x8*)(kb0 + (size_t)cb * 16 * (KV_ * DH_) + kb * 32);
        sc[cb] = __builtin_amdgcn_mfma_f32_16x16x32_bf16(qf[kb], kf, sc[cb], 0, 0, 0);
      }
    }
    float pv[2][4];
#pragma unroll
    for (int j = 0; j < 4; ++j) {
      int t = t0 + lg * 4 + j;
      int s_a = s0 + l15, s_b = s_a + 16;
      float va = sc[0][j] * kScale;
      float vb = sc[1][j] * kScale;
      va = (s_a <= t && s_a + (WWIN - 1) >= t) ? va : -INFINITY;
      vb = (s_b <= t && s_b + (WWIN - 1) >= t) ? vb : -INFINITY;
      float mx = fmaxf(va, vb);
#pragma unroll
      for (int off = 1; off < 16; off <<= 1) mx = fmaxf(mx, __shfl_xor(mx, off));
      float mn = fmaxf(m_r[j], mx);
      float alpha, pa, pb;
      if (mn == -INFINITY) { alpha = 1.f; pa = 0.f; pb = 0.f; }
      else {
        alpha = __expf(m_r[j] - mn);
        pa = __expf(va - mn);
        pb = __expf(vb - mn);
      }
      m_r[j] = mn;
      float rs = pa + pb;
#pragma unroll
      for (int off = 1; off < 16; off <<= 1) rs += __shfl_xor(rs, off);
      l_r[j] = l_r[j] * alpha + rs;
#pragma unroll
      for (int nb = 0; nb < 8; ++nb) of[nb][j] *= alpha;
      pv[0][j] = pa; pv[1][j] = pb;
    }
#pragma unroll
    for (int cb = 0; cb < 2; ++cb)
#pragma unroll
      for (int j = 0; j < 4; ++j)
        pl[w][lg * 4 + j][cb * 16 + l15] = f2bf(pv[cb][j]);
    asm volatile("s_waitcnt lgkmcnt(0)" ::: "memory");
    __builtin_amdgcn_sched_barrier(0);
    s16x8 pa8 = *(const s16x8*)&pl[w][l15][lg * 8];
    const unsigned short* vb0 = vbf + ((size_t)(b * T_ + s0 + lg * 8) * KVSTR) + kvh * DH_ + l15;
#pragma unroll
    for (int nb = 0; nb < 8; ++nb) {
      s16x8 vf;
#pragma unroll
      for (int jj = 0; jj < 8; ++jj) vf[jj] = (short)vb0[(size_t)jj * KVSTR + nb * 16];
      of[nb] = __builtin_amdgcn_mfma_f32_16x16x32_bf16(pa8, vf, of[nb], 0, 0, 0);
    }
  }
  float inv[4];
#pragma unroll
  for (int j = 0; j < 4; ++j) inv[j] = 1.f / l_r[j];
#pragma unroll
  for (int nb = 0; nb < 8; ++nb)
#pragma unroll
    for (int j = 0; j < 4; ++j) {
      int t = t0 + lg * 4 + j;
      olocal[(size_t)(b * T_ + t) * D_ + h * DH_ + nb * 16 + l15] = f2bf(of[nb][j] * inv[j]);
    }
}

// ---------------- host launcher ----------------
extern "C" void kernel_launch(void* const* d_in, const int* in_sizes, int n_in,
                              void* d_out, int out_size, void* d_ws, size_t ws_size,
                              hipStream_t stream) {
  const float* hs   = (const float*)d_in[0];
  const float* cosp = (const float*)d_in[1];
  const float* sinp = (const float*)d_in[2];
  const float* mem  = (const float*)d_in[3];
  const float* Wq   = (const float*)d_in[4];
  const float* Wk   = (const float*)d_in[5];
  const float* Wv   = (const float*)d_in[6];
  const float* Wo   = (const float*)d_in[7];
  const float* Wg   = (const float*)d_in[8];
  const float* bg   = (const float*)d_in[9];
  float* out = (float*)d_out;

  char* p = (char*)d_ws;
  auto alloc = [&](size_t bytes) { char* r = p; p += (bytes + 255) & ~(size_t)255; return r; };
  // small buffers first, then big. Total ~92.8 MB.
  float* qc     = (float*)alloc((size_t)B_ * H_ * DH_ * 4);
  float* ksh    = (float*)alloc((size_t)B_ * H_ * KSEL * DH_ * 4);
  float* vsh    = (float*)alloc((size_t)B_ * H_ * KSEL * DH_ * 4);
  float* gbuf   = (float*)alloc((size_t)BT * 4);
  float* zbuf   = (float*)alloc((size_t)B_ * H_ * D_ * 4);
  float* simbuf = (float*)alloc((size_t)B_ * H_ * NMEM * 4);
  int*   idxbuf = (int*)alloc((size_t)B_ * H_ * KSEL * 4);
  unsigned short* hs_bf  = (unsigned short*)alloc((size_t)BT * D_ * 2);   // -> o_mem bf16 later
  unsigned short* q_raw  = (unsigned short*)alloc((size_t)BT * D_ * 2);   // -> C/S partials -> o_local
  unsigned short* q_bf   = (unsigned short*)alloc((size_t)BT * D_ * 2);
  unsigned short* kv_raw = (unsigned short*)alloc((size_t)BT * KVSTR * 2); // K cols [0,1024) | V cols [1024,2048)
  unsigned short* k_bf   = (unsigned short*)alloc((size_t)BT * KV_ * DH_ * 2);
  unsigned short* wbig   = (unsigned short*)alloc((size_t)D_ * D_ * 2);   // Wq -> Wk|Wv -> Wo

  float* Cp = (float*)q_raw;                       // 4 partials: 4*B*128*2048 floats
  float* Sp = Cp + (size_t)4 * B_ * DH_ * D_;
  unsigned short* o_local = q_raw;                 // after qchunk, q_raw is dead again
  unsigned short* omem_bf = hs_bf;                 // after KV-gemm, hs_bf is dead

  // 1) conversions + projections (bf16 MFMA)
  conv_kernel<<<(BT * D_ / 4 + 255) / 256, 256, 0, stream>>>(hs, hs_bf, BT * D_);
  conv_kernel<<<(D_ * D_ / 4 + 255) / 256, 256, 0, stream>>>(Wq, wbig, D_ * D_);
  gemm_bt<0><<<dim3(D_ / 128, BT / 128), 256, 0, stream>>>(hs_bf, wbig, D_, D_, q_raw, nullptr, nullptr, nullptr);
  conv_kernel<<<(KV_ * DH_ * D_ / 4 + 255) / 256, 256, 0, stream>>>(Wk, wbig, KV_ * DH_ * D_);
  conv_kernel<<<(KV_ * DH_ * D_ / 4 + 255) / 256, 256, 0, stream>>>(Wv, wbig + (size_t)KV_ * DH_ * D_, KV_ * DH_ * D_);
  gemm_bt<0><<<dim3(KVSTR / 128, BT / 128), 256, 0, stream>>>(hs_bf, wbig, KVSTR, D_, kv_raw, nullptr, nullptr, nullptr);

  // 2) RoPE (q in q_raw -> q_bf; k half of kv_raw -> k_bf)
  rope_kernel<<<BT * D_ / 256, 256, 0, stream>>>(q_raw, q_bf, cosp, sinp, 11, D_, BT * D_);
  rope_kernel<<<BT * KV_ * DH_ / 256, 256, 0, stream>>>(kv_raw, k_bf, cosp, sinp, 10, KVSTR, BT * KV_ * DH_);

  // 3) exact-fp32 selection path (q_raw now dead -> holds C/S partials)
  cs_kernel<<<dim3(D_ / 128, DH_ / 32, B_ * 4), 256, 0, stream>>>(hs, cosp, sinp, Cp, Sp);
  qchunk_kernel<<<(B_ * H_ * DH_) / 4, 256, 0, stream>>>(Wq, Cp, Sp, qc);
  zk_kernel<<<dim3(D_ / 256, H_, B_), 256, 0, stream>>>(qc, Wk, zbuf);
  sim_kernel<<<dim3(NMEM / 16, B_), 256, 0, stream>>>(zbuf, mem, simbuf);
  topk_kernel<<<dim3(H_, B_), 256, 0, stream>>>(simbuf, idxbuf);
  gproj_kernel<<<dim3(2, H_, B_), 256, 0, stream>>>(idxbuf, Wk, Wv, mem, ksh, vsh);

  // 4) memory-branch attention -> o_mem bf16 (reuses hs_bf)
  memattn_kernel<<<dim3(T_ / 256, H_, B_), 256, 0, stream>>>(q_bf, ksh, vsh, omem_bf);

  // 5) gate
  gate_kernel<<<BT / 4, 256, 0, stream>>>(hs, Wg, bg, gbuf);

  // 6) local sliding-window attention (o_local reuses q_raw; launched after qchunk)
  localattn_kernel<<<dim3(T_ / 64, H_, B_), 256, 0, stream>>>(q_bf, k_bf, kv_raw + (size_t)KV_ * DH_, o_local);

  // 7) Wo projection + final combine (d_out pure write)
  conv_kernel<<<(D_ * D_ / 4 + 255) / 256, 256, 0, stream>>>(Wo, wbig, D_ * D_);
  gemm_bt<1><<<dim3(D_ / 128, BT / 128), 256, 0, stream>>>(o_local, wbig, D_, D_, nullptr, gbuf, omem_bf, out);
}

// Round 5
// 532.582 us; speedup vs baseline: 1.9020x; 1.1627x over previous
//
#include <hip/hip_runtime.h>
#include <stdint.h>

#define B_   2
#define T_   2048
#define D_   2048
#define H_   16
#define KV_  8
#define DH_  128
#define NMEM 1024
#define WWIN 256
#define KSEL 8
#define BT   (B_*T_)
#define KVSTR 2048   // merged KV row stride (elements)

__constant__ const float kScale = 0.08838834764831845f; // DH^-0.5

typedef __attribute__((ext_vector_type(8))) short s16x8;
typedef __attribute__((ext_vector_type(4))) float f32x4;

__device__ inline unsigned short f2bf(float f) {
  union { float f; unsigned int u; } c; c.f = f;
  unsigned int u = c.u;
  unsigned int r = u + 0x7fffu + ((u >> 16) & 1u);
  return (unsigned short)(r >> 16);
}
__device__ inline float bf2f(unsigned short v) {
  union { unsigned int u; float f; } c; c.u = ((unsigned int)v) << 16;
  return c.f;
}
__device__ inline f32x4 fzero4() { f32x4 v; v[0]=0.f; v[1]=0.f; v[2]=0.f; v[3]=0.f; return v; }

// ---------------- fp32 -> bf16 conversion (float4 wide) ----------------
__global__ __launch_bounds__(256) void conv_kernel(const float* __restrict__ src,
                                                   unsigned short* __restrict__ dst, int n) {
  int i = blockIdx.x * 256 + threadIdx.x;
  if (i * 4 >= n) return;
  float4 v = ((const float4*)src)[i];
  uint2 o;
  o.x = (unsigned)f2bf(v.x) | ((unsigned)f2bf(v.y) << 16);
  o.y = (unsigned)f2bf(v.z) | ((unsigned)f2bf(v.w) << 16);
  ((uint2*)dst)[i] = o;
}

// ---------------- bf16 GEMM: C[M,N] = A[M,K] @ B[N,K]^T ----------------
// MODE 0: write bf16 C.
// MODE 1: dout = g[row]*acc + (1-g[row])*bf2f(omem[o])   (d_out pure write)
template<int MODE>
__global__ __launch_bounds__(256) void gemm_bt(const unsigned short* __restrict__ A,
                                               const unsigned short* __restrict__ Bw,
                                               int N, int K,
                                               unsigned short* __restrict__ Cb,
                                               const float* __restrict__ g,
                                               const unsigned short* __restrict__ omem,
                                               float* __restrict__ dout) {
  __shared__ __align__(16) unsigned short sA[128 * 32];
  __shared__ __align__(16) unsigned short sB[128 * 32];
  const int tid = threadIdx.x;
  const int wv = tid >> 6, lane = tid & 63;
  // XCD-aware bijective swizzle (nwg % 8 == 0 for all our launches)
  const int gx = gridDim.x;
  const int nwg = gx * gridDim.y;
  const int flat = blockIdx.y * gx + blockIdx.x;
  const int chunk = nwg >> 3;
  const int wg = (flat & 7) * chunk + (flat >> 3);
  const int bx = wg % gx, by = wg / gx;
  const int m0 = by * 128, n0 = bx * 128;
  const int wr = wv >> 1, wc = wv & 1;
  const int l15 = lane & 15, lg = lane >> 4;
  const int rowA = tid >> 2;
  const int colB = (tid & 3) * 16; // bytes
  f32x4 acc[4][4];
#pragma unroll
  for (int mi = 0; mi < 4; ++mi)
#pragma unroll
    for (int ni = 0; ni < 4; ++ni) acc[mi][ni] = fzero4();

  char* sAc = (char*)sA;
  char* sBc = (char*)sB;
  for (int k0 = 0; k0 < K; k0 += 32) {
#pragma unroll
    for (int e = 0; e < 2; ++e) {
      const char* ga = (const char*)(A + ((size_t)(m0 + rowA + e * 64) * K + k0)) + colB;
      __builtin_amdgcn_global_load_lds((const __attribute__((address_space(1))) void*)ga,
          (__attribute__((address_space(3))) void*)(sAc + e * 4096 + wv * 1024), 16, 0, 0);
      const char* gb = (const char*)(Bw + ((size_t)(n0 + rowA + e * 64) * K + k0)) + colB;
      __builtin_amdgcn_global_load_lds((const __attribute__((address_space(1))) void*)gb,
          (__attribute__((address_space(3))) void*)(sBc + e * 4096 + wv * 1024), 16, 0, 0);
    }
    __syncthreads();
    s16x8 af[4], bf_[4];
#pragma unroll
    for (int mi = 0; mi < 4; ++mi)
      af[mi] = *(const s16x8*)&sA[(wr * 64 + mi * 16 + l15) * 32 + lg * 8];
#pragma unroll
    for (int ni = 0; ni < 4; ++ni)
      bf_[ni] = *(const s16x8*)&sB[(wc * 64 + ni * 16 + l15) * 32 + lg * 8];
#pragma unroll
    for (int mi = 0; mi < 4; ++mi)
#pragma unroll
      for (int ni = 0; ni < 4; ++ni)
        acc[mi][ni] = __builtin_amdgcn_mfma_f32_16x16x32_bf16(af[mi], bf_[ni], acc[mi][ni], 0, 0, 0);
    __syncthreads();
  }
#pragma unroll
  for (int mi = 0; mi < 4; ++mi)
#pragma unroll
    for (int ni = 0; ni < 4; ++ni)
#pragma unroll
      for (int j = 0; j < 4; ++j) {
        int row_g = m0 + wr * 64 + mi * 16 + lg * 4 + j;
        int col_g = n0 + wc * 64 + ni * 16 + l15;
        float v = acc[mi][ni][j];
        if constexpr (MODE == 0) {
          Cb[(size_t)row_g * N + col_g] = f2bf(v);
        } else {
          float gv = g[row_g];
          size_t o = (size_t)row_g * N + col_g;
          float om = bf2f(omem[o]);
          dout[o] = gv * v + (1.f - gv) * om;
        }
      }
}

// ---------------- in-place pairwise RoPE (bf16) ----------------
// Each thread processes 8 (d, d+64) pairs in one 128-wide head block.
// logp = log2(pairs per row); stride = row stride in elements.
__global__ __launch_bounds__(256) void rope_ip_kernel(unsigned short* __restrict__ buf,
                                                      const float* __restrict__ cosp,
                                                      const float* __restrict__ sinp,
                                                      int logp, int stride, int nthreads) {
  int i = blockIdx.x * 256 + threadIdx.x;
  if (i >= nthreads) return;
  int pp = i * 8;
  int row = pp >> logp;
  int p0 = pp & ((1 << logp) - 1);
  int blk = p0 >> 6, dd0 = p0 & 63;
  int b = row >> 11, t = row & 2047;
  const float* cb = cosp + ((size_t)b * T_ + t) * DH_;
  const float* sb = sinp + ((size_t)b * T_ + t) * DH_;
  unsigned short* p1 = buf + (size_t)row * stride + blk * 128 + dd0;
  s16x8 a = *(s16x8*)p1;
  s16x8 b8 = *(s16x8*)(p1 + 64);
  s16x8 o1, o2;
#pragma unroll
  for (int e = 0; e < 8; ++e) {
    float c1 = cb[dd0 + e], s1 = sb[dd0 + e];
    float c2 = cb[dd0 + 64 + e], s2 = sb[dd0 + 64 + e];
    float x1 = bf2f((unsigned short)a[e]), x2 = bf2f((unsigned short)b8[e]);
    o1[e] = (short)f2bf(x1 * c1 - x2 * s1);
    o2[e] = (short)f2bf(x2 * c2 + x1 * s2);
  }
  *(s16x8*)p1 = o1;
  *(s16x8*)(p1 + 64) = o2;
}

// ---------------- C/S partials: Cp[sp,b,d,j] = sum_{t in sp} cos[b,t,d]*hs[b,t,j] ----------------
__global__ __launch_bounds__(256) void cs_kernel(const float* __restrict__ hs,
                                                 const float* __restrict__ cosp,
                                                 const float* __restrict__ sinp,
                                                 float* __restrict__ Cp, float* __restrict__ Sp) {
  __shared__ __align__(16) float hsL[32][128];
  __shared__ __align__(16) float csL[32][32];
  __shared__ __align__(16) float snL[32][32];
  const int tid = threadIdx.x;
  const int j0 = blockIdx.x * 128, d0 = blockIdx.y * 32;
  const int b = blockIdx.z >> 2, sp = blockIdx.z & 3;
  const int dq = (tid & 7) * 4;
  const int jq = (tid >> 3) * 4;
  float4 aC[4], aS[4];
#pragma unroll
  for (int a = 0; a < 4; ++a) {
    aC[a] = make_float4(0.f, 0.f, 0.f, 0.f);
    aS[a] = make_float4(0.f, 0.f, 0.f, 0.f);
  }
  const int csrow = tid >> 3, csc4 = tid & 7;
  for (int tile = 0; tile < 16; ++tile) {
    int t0 = sp * 512 + tile * 32;
    const float4* hs4 = (const float4*)(hs + ((size_t)b * T_ + t0) * D_ + j0);
#pragma unroll
    for (int r = 0; r < 4; ++r) {
      int i = tid + r * 256;
      int row = i >> 5, c4 = i & 31;
      *(float4*)&hsL[row][c4 * 4] = hs4[(size_t)row * (D_ / 4) + c4];
    }
    const float4* cp4 = (const float4*)(cosp + ((size_t)b * T_ + t0) * DH_ + d0);
    const float4* sp4 = (const float4*)(sinp + ((size_t)b * T_ + t0) * DH_ + d0);
    *(float4*)&csL[csrow][csc4 * 4] = cp4[(size_t)csrow * (DH_ / 4) + csc4];
    *(float4*)&snL[csrow][csc4 * 4] = sp4[(size_t)csrow * (DH_ / 4) + csc4];
    __syncthreads();
#pragma unroll 8
    for (int tt = 0; tt < 32; ++tt) {
      float4 cv = *(const float4*)&csL[tt][dq];
      float4 sv = *(const float4*)&snL[tt][dq];
      float4 hv = *(const float4*)&hsL[tt][jq];
      float ca[4] = {cv.x, cv.y, cv.z, cv.w};
      float sa[4] = {sv.x, sv.y, sv.z, sv.w};
#pragma unroll
      for (int a = 0; a < 4; ++a) {
        aC[a].x += ca[a] * hv.x; aC[a].y += ca[a] * hv.y;
        aC[a].z += ca[a] * hv.z; aC[a].w += ca[a] * hv.w;
        aS[a].x += sa[a] * hv.x; aS[a].y += sa[a] * hv.y;
        aS[a].z += sa[a] * hv.z; aS[a].w += sa[a] * hv.w;
      }
    }
    __syncthreads();
  }
#pragma unroll
  for (int a = 0; a < 4; ++a) {
    size_t o = ((size_t)(sp * B_ + b) * DH_ + d0 + dq + a) * D_ + j0 + jq;
    *(float4*)&Cp[o] = aC[a];
    *(float4*)&Sp[o] = aS[a];
  }
}

// ---------------- q_chunk[b,h,d] from 4 C/S partials (exact fp32) ----------------
__global__ __launch_bounds__(256) void qchunk_kernel(const float* __restrict__ Wq,
                                                     const float* __restrict__ Cp,
                                                     const float* __restrict__ Sp,
                                                     float* __restrict__ qc) {
  int gid = blockIdx.x * 256 + threadIdx.x;
  int wid = gid >> 6, lane = gid & 63;
  int b = wid >> 11, rem = wid & 2047;
  int h = rem >> 7, d = rem & 127;
  const float* w1 = Wq + (size_t)(h * DH_ + d) * D_;
  int dp = (d < 64) ? d + 64 : d - 64;
  float sgn = (d < 64) ? -1.f : 1.f;
  const float* w2 = Wq + (size_t)(h * DH_ + dp) * D_;
  float a1 = 0.f, a2 = 0.f;
#pragma unroll
  for (int p = 0; p < 4; ++p) {
    const float* crow = Cp + ((size_t)(p * B_ + b) * DH_ + d) * D_;
    const float* srow = Sp + ((size_t)(p * B_ + b) * DH_ + d) * D_;
    for (int j = lane; j < D_; j += 64) { a1 += w1[j] * crow[j]; a2 += w2[j] * srow[j]; }
  }
#pragma unroll
  for (int off = 1; off < 64; off <<= 1) { a1 += __shfl_xor(a1, off); a2 += __shfl_xor(a2, off); }
  if (lane == 0) qc[wid] = (a1 + sgn * a2) * (1.f / (float)T_);
}

// ---------------- z[b,h,j] = sum_d qc[b,h,d] * Wk[kvh*128+d][j]  (fp32 exact) ----------------
__global__ __launch_bounds__(256) void zk_kernel(const float* __restrict__ qc,
                                                 const float* __restrict__ Wk,
                                                 float* __restrict__ z) {
  int j = blockIdx.x * 256 + threadIdx.x;
  int h = blockIdx.y, b = blockIdx.z;
  int kvh = h >> 1;
  const float* qcl = qc + ((size_t)b * H_ + h) * DH_;
  const float* wb = Wk + (size_t)kvh * DH_ * D_ + j;
  float acc = 0.f;
#pragma unroll 8
  for (int d = 0; d < 128; ++d) acc += qcl[d] * wb[(size_t)d * D_];
  z[((size_t)b * H_ + h) * D_ + j] = acc;
}

// ---------------- sim[b,h,n] = kScale * z[b,h,:] . mem[b,n,:] ----------------
__global__ __launch_bounds__(256) void sim_kernel(const float* __restrict__ z,
                                                  const float* __restrict__ mem,
                                                  float* __restrict__ sim) {
  __shared__ float4 mL[16 * 512];   // 128 KB, XOR-swizzled rows
  int tid = threadIdx.x;
  int n0 = blockIdx.x * 16, b = blockIdx.y;
  const float4* mem4 = (const float4*)(mem + (size_t)b * NMEM * D_);
#pragma unroll
  for (int c = 0; c < 32; ++c) {
    int i = tid + c * 256;
    int r = i >> 9, j4 = i & 511;
    mL[r * 512 + (j4 ^ (r & 7))] = mem4[(size_t)(n0 + r) * 512 + j4];
  }
  __syncthreads();
  int h = tid >> 4, n = tid & 15;
  const float4* zr = (const float4*)(z + ((size_t)b * H_ + h) * D_);
  float acc = 0.f;
  for (int j4 = 0; j4 < 512; ++j4) {
    float4 zz = zr[j4];
    float4 mm = mL[n * 512 + (j4 ^ (n & 7))];
    acc += zz.x * mm.x + zz.y * mm.y + zz.z * mm.z + zz.w * mm.w;
  }
  sim[((size_t)b * H_ + h) * NMEM + n0 + n] = acc * kScale;
}

// ---------------- top-8 per (b,h) (ties -> lowest index, matching lax.top_k) ----------------
__global__ __launch_bounds__(256) void topk_kernel(const float* __restrict__ sim,
                                                   int* __restrict__ idx) {
  __shared__ float sL[1024];
  __shared__ float rv[256];
  __shared__ int ri[256];
  int tid = threadIdx.x;
  int h = blockIdx.x, b = blockIdx.y;
  const float* sp = sim + ((size_t)b * H_ + h) * NMEM;
#pragma unroll
  for (int r = 0; r < 4; ++r) sL[tid + r * 256] = sp[tid + r * 256];
  __syncthreads();
  for (int kk = 0; kk < 8; ++kk) {
    float bv = -INFINITY; int bi = 0x7fffffff;
#pragma unroll
    for (int r = 0; r < 4; ++r) {
      int i = tid + r * 256;
      float v = sL[i];
      if (v > bv || (v == bv && i < bi)) { bv = v; bi = i; }
    }
    rv[tid] = bv; ri[tid] = bi;
    __syncthreads();
    for (int s = 128; s > 0; s >>= 1) {
      if (tid < s) {
        float v2 = rv[tid + s]; int i2 = ri[tid + s];
        if (v2 > rv[tid] || (v2 == rv[tid] && i2 < ri[tid])) { rv[tid] = v2; ri[tid] = i2; }
      }
      __syncthreads();
    }
    if (tid == 0) { idx[((size_t)b * H_ + h) * KSEL + kk] = ri[0]; sL[ri[0]] = -INFINITY; }
    __syncthreads();
  }
}

// ---------------- memory-branch attention: gather K/V rows from kvmem (bf16) ----------------
__global__ __launch_bounds__(256) void memattn_kernel(const unsigned short* __restrict__ qbf,
                                                      const unsigned short* __restrict__ kvmem,
                                                      const int* __restrict__ idx,
                                                      unsigned short* __restrict__ omem) {
  __shared__ float kl[8][128];
  __shared__ float vl[8][128];
  __shared__ int selL[8];
  int tid = threadIdx.x;
  int b = blockIdx.z, h = blockIdx.y, t = blockIdx.x * 256 + tid;
  int kvh = h >> 1;
  if (tid < 8) selL[tid] = idx[((size_t)b * H_ + h) * KSEL + tid];
  __syncthreads();
  {
    int r = tid >> 5, c4 = (tid & 31) * 4;
    size_t rb = ((size_t)b * NMEM + selL[r]) * (size_t)KVSTR;
    ushort4 k4 = *(const ushort4*)(kvmem + rb + kvh * DH_ + c4);
    ushort4 v4 = *(const ushort4*)(kvmem + rb + KV_ * DH_ + kvh * DH_ + c4);
    kl[r][c4 + 0] = bf2f(k4.x); kl[r][c4 + 1] = bf2f(k4.y);
    kl[r][c4 + 2] = bf2f(k4.z); kl[r][c4 + 3] = bf2f(k4.w);
    vl[r][c4 + 0] = bf2f(v4.x); vl[r][c4 + 1] = bf2f(v4.y);
    vl[r][c4 + 2] = bf2f(v4.z); vl[r][c4 + 3] = bf2f(v4.w);
  }
  __syncthreads();
  float sc[8] = {0.f,0.f,0.f,0.f,0.f,0.f,0.f,0.f};
  const unsigned short* qr = qbf + (size_t)(b * T_ + t) * D_ + h * DH_;
  for (int c = 0; c < 4; ++c) {
    const s16x8* qp = (const s16x8*)(qr + c * 32);
#pragma unroll
    for (int u = 0; u < 4; ++u) {
      s16x8 q8 = qp[u];
#pragma unroll
      for (int e = 0; e < 8; ++e) {
        float qv = bf2f((unsigned short)q8[e]);
        int d = c * 32 + u * 8 + e;
#pragma unroll
        for (int kk = 0; kk < 8; ++kk) sc[kk] += qv * kl[kk][d];
      }
    }
  }
  float sm[8], mx = -INFINITY;
#pragma unroll
  for (int kk = 0; kk < 8; ++kk) { sm[kk] = sc[kk] * kScale; mx = fmaxf(mx, sm[kk]); }
  float sum = 0.f;
#pragma unroll
  for (int kk = 0; kk < 8; ++kk) { sm[kk] = __expf(sm[kk] - mx); sum += sm[kk]; }
  float inv = 1.f / sum;
#pragma unroll
  for (int kk = 0; kk < 8; ++kk) sm[kk] *= inv;
  unsigned short* orow = omem + (size_t)(b * T_ + t) * D_ + h * DH_;
  for (int d = 0; d < 128; d += 4) {
    float o0 = 0.f, o1 = 0.f, o2 = 0.f, o3 = 0.f;
#pragma unroll
    for (int kk = 0; kk < 8; ++kk) {
      float w = sm[kk];
      o0 += w * vl[kk][d + 0];
      o1 += w * vl[kk][d + 1];
      o2 += w * vl[kk][d + 2];
      o3 += w * vl[kk][d + 3];
    }
    uint2 pk;
    pk.x = (unsigned)f2bf(o0) | ((unsigned)f2bf(o1) << 16);
    pk.y = (unsigned)f2bf(o2) | ((unsigned)f2bf(o3) << 16);
    *(uint2*)(orow + d) = pk;
  }
}

// ---------------- gate: g = sigmoid(hs . Wg + bg) ----------------
__global__ __launch_bounds__(256) void gate_kernel(const float* __restrict__ hs,
                                                   const float* __restrict__ Wg,
                                                   const float* __restrict__ bg,
                                                   float* __restrict__ g) {
  int gid = blockIdx.x * 256 + threadIdx.x;
  int row = gid >> 6, lane = gid & 63;
  const float4* hr = (const float4*)(hs + (size_t)row * D_);
  const float4* wg4 = (const float4*)Wg;
  float acc = 0.f;
#pragma unroll
  for (int it = 0; it < 8; ++it) {
    float4 hv = hr[lane + it * 64], wv = wg4[lane + it * 64];
    acc += hv.x * wv.x + hv.y * wv.y + hv.z * wv.z + hv.w * wv.w;
  }
#pragma unroll
  for (int off = 1; off < 64; off <<= 1) acc += __shfl_xor(acc, off);
  if (lane == 0) g[row] = 1.f / (1.f + __expf(-(acc + bg[0])));
}

// ---------------- local sliding-window attention (flash, per-wave 16 rows) ----------------
// kbf: roped K inside merged KV buffer (cols [0,1024)), vbf: V cols; both row stride KVSTR.
__global__ __launch_bounds__(256) void localattn_kernel(const unsigned short* __restrict__ qbf,
                                                        const unsigned short* __restrict__ kbf,
                                                        const unsigned short* __restrict__ vbf,
                                                        unsigned short* __restrict__ olocal) {
  __shared__ __align__(16) unsigned short pl[4][16][40];
  const int tid = threadIdx.x;
  const int w = tid >> 6, lane = tid & 63;
  const int tb = blockIdx.x * 64;
  const int h = blockIdx.y, b = blockIdx.z;
  const int kvh = h >> 1;
  const int t0 = tb + w * 16;
  const int l15 = lane & 15, lg = lane >> 4;

  s16x8 qf[4];
  {
    const unsigned short* qb = qbf + ((size_t)(b * T_ + t0 + l15) * D_) + h * DH_ + lg * 8;
#pragma unroll
    for (int kb = 0; kb < 4; ++kb) qf[kb] = *(const s16x8*)(qb + kb * 32);
  }
  f32x4 of[8];
#pragma unroll
  for (int nb = 0; nb < 8; ++nb) of[nb] = fzero4();
  float m_r[4] = {-INFINITY, -INFINITY, -INFINITY, -INFINITY};
  float l_r[4] = {0.f, 0.f, 0.f, 0.f};

  int sstart = t0 - (WWIN - 1);
  if (sstart < 0) sstart = 0;
  sstart &= ~31;
  for (int s0 = sstart; s0 <= t0 + 15; s0 += 32) {
    f32x4 sc[2];
    sc[0] = fzero4(); sc[1] = fzero4();
    const unsigned short* kb0 = kbf + ((size_t)(b * T_ + s0 + l15) * KVSTR) + kvh * DH_ + lg * 8;
#pragma unroll
    for (int cb = 0; cb < 2; ++cb) {
#pragma unroll
      for (int kb = 0; kb < 4; ++kb) {
        s16x8 kf = *(const s16x8*)(kb0 + (size_t)cb * 16 * KVSTR + kb * 32);
        sc[cb] = __builtin_amdgcn_mfma_f32_16x16x32_bf16(qf[kb], kf, sc[cb], 0, 0, 0);
      }
    }
    float pv[2][4];
#pragma unroll
    for (int j = 0; j < 4; ++j) {
      int t = t0 + lg * 4 + j;
      int s_a = s0 + l15, s_b = s_a + 16;
      float va = sc[0][j] * kScale;
      float vb = sc[1][j] * kScale;
      va = (s_a <= t && s_a + (WWIN - 1) >= t) ? va : -INFINITY;
      vb = (s_b <= t && s_b + (WWIN - 1) >= t) ? vb : -INFINITY;
      float mx = fmaxf(va, vb);
#pragma unroll
      for (int off = 1; off < 16; off <<= 1) mx = fmaxf(mx, __shfl_xor(mx, off));
      float mn = fmaxf(m_r[j], mx);
      float alpha, pa, pb;
      if (mn == -INFINITY) { alpha = 1.f; pa = 0.f; pb = 0.f; }
      else {
        alpha = __expf(m_r[j] - mn);
        pa = __expf(va - mn);
        pb = __expf(vb - mn);
      }
      m_r[j] = mn;
      float rs = pa + pb;
#pragma unroll
      for (int off = 1; off < 16; off <<= 1) rs += __shfl_xor(rs, off);
      l_r[j] = l_r[j] * alpha + rs;
#pragma unroll
      for (int nb = 0; nb < 8; ++nb) of[nb][j] *= alpha;
      pv[0][j] = pa; pv[1][j] = pb;
    }
#pragma unroll
    for (int cb = 0; cb < 2; ++cb)
#pragma unroll
      for (int j = 0; j < 4; ++j)
        pl[w][lg * 4 + j][cb * 16 + l15] = f2bf(pv[cb][j]);
    asm volatile("s_waitcnt lgkmcnt(0)" ::: "memory");
    __builtin_amdgcn_sched_barrier(0);
    s16x8 pa8 = *(const s16x8*)&pl[w][l15][lg * 8];
    const unsigned short* vb0 = vbf + ((size_t)(b * T_ + s0 + lg * 8) * KVSTR) + kvh * DH_ + l15;
#pragma unroll
    for (int nb = 0; nb < 8; ++nb) {
      s16x8 vf;
#pragma unroll
      for (int jj = 0; jj < 8; ++jj) vf[jj] = (short)vb0[(size_t)jj * KVSTR + nb * 16];
      of[nb] = __builtin_amdgcn_mfma_f32_16x16x32_bf16(pa8, vf, of[nb], 0, 0, 0);
    }
  }
  float inv[4];
#pragma unroll
  for (int j = 0; j < 4; ++j) inv[j] = 1.f / l_r[j];
#pragma unroll
  for (int nb = 0; nb < 8; ++nb)
#pragma unroll
    for (int j = 0; j < 4; ++j) {
      int t = t0 + lg * 4 + j;
      olocal[(size_t)(b * T_ + t) * D_ + h * DH_ + nb * 16 + l15] = f2bf(of[nb][j] * inv[j]);
    }
}

// ---------------- host launcher ----------------
extern "C" void kernel_launch(void* const* d_in, const int* in_sizes, int n_in,
                              void* d_out, int out_size, void* d_ws, size_t ws_size,
                              hipStream_t stream) {
  const float* hs   = (const float*)d_in[0];
  const float* cosp = (const float*)d_in[1];
  const float* sinp = (const float*)d_in[2];
  const float* mem  = (const float*)d_in[3];
  const float* Wq   = (const float*)d_in[4];
  const float* Wk   = (const float*)d_in[5];
  const float* Wv   = (const float*)d_in[6];
  const float* Wo   = (const float*)d_in[7];
  const float* Wg   = (const float*)d_in[8];
  const float* bg   = (const float*)d_in[9];
  float* out = (float*)d_out;

  char* p = (char*)d_ws;
  auto alloc = [&](size_t bytes) { char* r = p; p += (bytes + 255) & ~(size_t)255; return r; };
  // small buffers first, then big. Total ~84.5 MB.
  float* qc     = (float*)alloc((size_t)B_ * H_ * DH_ * 4);
  float* gbuf   = (float*)alloc((size_t)BT * 4);
  float* zbuf   = (float*)alloc((size_t)B_ * H_ * D_ * 4);
  float* simbuf = (float*)alloc((size_t)B_ * H_ * NMEM * 4);
  int*   idxbuf = (int*)alloc((size_t)B_ * H_ * KSEL * 4);
  unsigned short* hs_bf  = (unsigned short*)alloc((size_t)BT * D_ * 2);    // -> o_mem bf16 later
  unsigned short* q_raw  = (unsigned short*)alloc((size_t)BT * D_ * 2);    // q -> roped q -> o_local (in place)
  unsigned short* kv_raw = (unsigned short*)alloc((size_t)BT * KVSTR * 2); // K cols [0,1024) | V cols [1024,2048)
  unsigned short* wbig   = (unsigned short*)alloc((size_t)D_ * D_ * 2);    // Wq -> Wk|Wv -> Wo
  unsigned short* mem_bf = (unsigned short*)alloc((size_t)B_ * NMEM * D_ * 2); // -> Cp later
  unsigned short* kvmem  = (unsigned short*)alloc((size_t)B_ * NMEM * KVSTR * 2);
  float* Sp = (float*)alloc((size_t)4 * B_ * DH_ * D_ * 4);

  float* Cp = (float*)mem_bf;            // after kvmem-gemm, mem_bf is dead (8.4 MB, exact fit)
  unsigned short* o_local = q_raw;       // localattn writes its own (t,h)-slice after reading it
  unsigned short* omem_bf = hs_bf;       // after kv-gemm, hs_bf is dead

  // 1) conversions + projections (bf16 MFMA)
  conv_kernel<<<(BT * D_ / 4 + 255) / 256, 256, 0, stream>>>(hs, hs_bf, BT * D_);
  conv_kernel<<<(D_ * D_ / 4 + 255) / 256, 256, 0, stream>>>(Wq, wbig, D_ * D_);
  gemm_bt<0><<<dim3(D_ / 128, BT / 128), 256, 0, stream>>>(hs_bf, wbig, D_, D_, q_raw, nullptr, nullptr, nullptr);
  conv_kernel<<<(KV_ * DH_ * D_ / 4 + 255) / 256, 256, 0, stream>>>(Wk, wbig, KV_ * DH_ * D_);
  conv_kernel<<<(KV_ * DH_ * D_ / 4 + 255) / 256, 256, 0, stream>>>(Wv, wbig + (size_t)KV_ * DH_ * D_, KV_ * DH_ * D_);
  gemm_bt<0><<<dim3(KVSTR / 128, BT / 128), 256, 0, stream>>>(hs_bf, wbig, KVSTR, D_, kv_raw, nullptr, nullptr, nullptr);
  // kvmem = mem_bf @ (Wk|Wv)^T  (values only; selection stays fp32)
  conv_kernel<<<(B_ * NMEM * D_ / 4 + 255) / 256, 256, 0, stream>>>(mem, mem_bf, B_ * NMEM * D_);
  gemm_bt<0><<<dim3(KVSTR / 128, (B_ * NMEM) / 128), 256, 0, stream>>>(mem_bf, wbig, KVSTR, D_, kvmem, nullptr, nullptr, nullptr);

  // 2) in-place RoPE (q: 1024 pairs/row; k: 512 pairs/row inside kv_raw)
  rope_ip_kernel<<<(BT * D_ / 16 + 255) / 256, 256, 0, stream>>>(q_raw, cosp, sinp, 10, D_, BT * D_ / 16);
  rope_ip_kernel<<<(BT * KV_ * DH_ / 16 + 255) / 256, 256, 0, stream>>>(kv_raw, cosp, sinp, 9, KVSTR, BT * KV_ * DH_ / 16);

  // 3) exact-fp32 selection path
  cs_kernel<<<dim3(D_ / 128, DH_ / 32, B_ * 4), 256, 0, stream>>>(hs, cosp, sinp, Cp, Sp);
  qchunk_kernel<<<(B_ * H_ * DH_) / 4, 256, 0, stream>>>(Wq, Cp, Sp, qc);
  zk_kernel<<<dim3(D_ / 256, H_, B_), 256, 0, stream>>>(qc, Wk, zbuf);
  sim_kernel<<<dim3(NMEM / 16, B_), 256, 0, stream>>>(zbuf, mem, simbuf);
  topk_kernel<<<dim3(H_, B_), 256, 0, stream>>>(simbuf, idxbuf);

  // 4) memory-branch attention (gathers K/V from kvmem) -> o_mem bf16 (reuses hs_bf)
  memattn_kernel<<<dim3(T_ / 256, H_, B_), 256, 0, stream>>>(q_raw, kvmem, idxbuf, omem_bf);

  // 5) gate
  gate_kernel<<<BT / 4, 256, 0, stream>>>(hs, Wg, bg, gbuf);

  // 6) local sliding-window attention (writes o_local in place over q_raw)
  localattn_kernel<<<dim3(T_ / 64, H_, B_), 256, 0, stream>>>(q_raw, kv_raw, kv_raw + (size_t)KV_ * DH_, o_local);

  // 7) Wo projection + final combine (d_out pure write)
  conv_kernel<<<(D_ * D_ / 4 + 255) / 256, 256, 0, stream>>>(Wo, wbig, D_ * D_);
  gemm_bt<1><<<dim3(D_ / 128, BT / 128), 256, 0, stream>>>(o_local, wbig, D_, D_, nullptr, gbuf, omem_bf, out);
}

// Round 6
// 500.551 us; speedup vs baseline: 2.0237x; 1.0640x over previous
//
#include <hip/hip_runtime.h>
#include <stdint.h>

#define B_   2
#define T_   2048
#define D_   2048
#define H_   16
#define KV_  8
#define DH_  128
#define NMEM 1024
#define WWIN 256
#define KSEL 8
#define BT   (B_*T_)
#define KVSTR 2048    // kvmem row stride (elements)
#define QKVSTR 4096   // merged qkv row stride (elements)

__constant__ const float kScale = 0.08838834764831845f; // DH^-0.5

typedef __attribute__((ext_vector_type(8))) short s16x8;
typedef __attribute__((ext_vector_type(4))) float f32x4;

__device__ inline unsigned short f2bf(float f) {
  union { float f; unsigned int u; } c; c.f = f;
  unsigned int u = c.u;
  unsigned int r = u + 0x7fffu + ((u >> 16) & 1u);
  return (unsigned short)(r >> 16);
}
__device__ inline float bf2f(unsigned short v) {
  union { unsigned int u; float f; } c; c.u = ((unsigned int)v) << 16;
  return c.f;
}
__device__ inline f32x4 fzero4() { f32x4 v; v[0]=0.f; v[1]=0.f; v[2]=0.f; v[3]=0.f; return v; }

// ---------------- fp32 -> bf16 conversion (float4 wide) ----------------
__global__ __launch_bounds__(256) void conv_kernel(const float* __restrict__ src,
                                                   unsigned short* __restrict__ dst, int n) {
  int i = blockIdx.x * 256 + threadIdx.x;
  if (i * 4 >= n) return;
  float4 v = ((const float4*)src)[i];
  uint2 o;
  o.x = (unsigned)f2bf(v.x) | ((unsigned)f2bf(v.y) << 16);
  o.y = (unsigned)f2bf(v.z) | ((unsigned)f2bf(v.w) << 16);
  ((uint2*)dst)[i] = o;
}

// ---------------- bf16 GEMM: C[M,N] = A[M,K](lda) @ B[N,K]^T, C stride ldc ----------------
// MODE 0: write bf16 C.
// MODE 1: dout = g[row]*acc + (1-g[row])*bf2f(omem[o])   (d_out pure write)
template<int MODE>
__global__ __launch_bounds__(256) void gemm_bt(const unsigned short* __restrict__ A,
                                               const unsigned short* __restrict__ Bw,
                                               int N, int K, int lda, int ldc,
                                               unsigned short* __restrict__ Cb,
                                               const float* __restrict__ g,
                                               const unsigned short* __restrict__ omem,
                                               float* __restrict__ dout) {
  __shared__ __align__(16) unsigned short sA[128 * 32];
  __shared__ __align__(16) unsigned short sB[128 * 32];
  const int tid = threadIdx.x;
  const int wv = tid >> 6, lane = tid & 63;
  // XCD-aware bijective swizzle (nwg % 8 == 0 for all our launches)
  const int gx = gridDim.x;
  const int nwg = gx * gridDim.y;
  const int flat = blockIdx.y * gx + blockIdx.x;
  const int chunk = nwg >> 3;
  const int wg = (flat & 7) * chunk + (flat >> 3);
  const int bx = wg % gx, by = wg / gx;
  const int m0 = by * 128, n0 = bx * 128;
  const int wr = wv >> 1, wc = wv & 1;
  const int l15 = lane & 15, lg = lane >> 4;
  const int rowA = tid >> 2;
  const int colB = (tid & 3) * 16; // bytes
  f32x4 acc[4][4];
#pragma unroll
  for (int mi = 0; mi < 4; ++mi)
#pragma unroll
    for (int ni = 0; ni < 4; ++ni) acc[mi][ni] = fzero4();

  char* sAc = (char*)sA;
  char* sBc = (char*)sB;
  for (int k0 = 0; k0 < K; k0 += 32) {
#pragma unroll
    for (int e = 0; e < 2; ++e) {
      const char* ga = (const char*)(A + ((size_t)(m0 + rowA + e * 64) * lda + k0)) + colB;
      __builtin_amdgcn_global_load_lds((const __attribute__((address_space(1))) void*)ga,
          (__attribute__((address_space(3))) void*)(sAc + e * 4096 + wv * 1024), 16, 0, 0);
      const char* gb = (const char*)(Bw + ((size_t)(n0 + rowA + e * 64) * K + k0)) + colB;
      __builtin_amdgcn_global_load_lds((const __attribute__((address_space(1))) void*)gb,
          (__attribute__((address_space(3))) void*)(sBc + e * 4096 + wv * 1024), 16, 0, 0);
    }
    __syncthreads();
    s16x8 af[4], bf_[4];
#pragma unroll
    for (int mi = 0; mi < 4; ++mi)
      af[mi] = *(const s16x8*)&sA[(wr * 64 + mi * 16 + l15) * 32 + lg * 8];
#pragma unroll
    for (int ni = 0; ni < 4; ++ni)
      bf_[ni] = *(const s16x8*)&sB[(wc * 64 + ni * 16 + l15) * 32 + lg * 8];
#pragma unroll
    for (int mi = 0; mi < 4; ++mi)
#pragma unroll
      for (int ni = 0; ni < 4; ++ni)
        acc[mi][ni] = __builtin_amdgcn_mfma_f32_16x16x32_bf16(af[mi], bf_[ni], acc[mi][ni], 0, 0, 0);
    __syncthreads();
  }
#pragma unroll
  for (int mi = 0; mi < 4; ++mi)
#pragma unroll
    for (int ni = 0; ni < 4; ++ni)
#pragma unroll
      for (int j = 0; j < 4; ++j) {
        int row_g = m0 + wr * 64 + mi * 16 + lg * 4 + j;
        int col_g = n0 + wc * 64 + ni * 16 + l15;
        float v = acc[mi][ni][j];
        size_t o = (size_t)row_g * ldc + col_g;
        if constexpr (MODE == 0) {
          Cb[o] = f2bf(v);
        } else {
          float gv = g[row_g];
          float om = bf2f(omem[o]);
          dout[o] = gv * v + (1.f - gv) * om;
        }
      }
}

// ---------------- in-place pairwise RoPE (bf16) ----------------
__global__ __launch_bounds__(256) void rope_ip_kernel(unsigned short* __restrict__ buf,
                                                      const float* __restrict__ cosp,
                                                      const float* __restrict__ sinp,
                                                      int logp, int stride, int nthreads) {
  int i = blockIdx.x * 256 + threadIdx.x;
  if (i >= nthreads) return;
  int pp = i * 8;
  int row = pp >> logp;
  int p0 = pp & ((1 << logp) - 1);
  int blk = p0 >> 6, dd0 = p0 & 63;
  int b = row >> 11, t = row & 2047;
  const float* cb = cosp + ((size_t)b * T_ + t) * DH_;
  const float* sb = sinp + ((size_t)b * T_ + t) * DH_;
  unsigned short* p1 = buf + (size_t)row * stride + blk * 128 + dd0;
  s16x8 a = *(s16x8*)p1;
  s16x8 b8 = *(s16x8*)(p1 + 64);
  s16x8 o1, o2;
#pragma unroll
  for (int e = 0; e < 8; ++e) {
    float c1 = cb[dd0 + e], s1 = sb[dd0 + e];
    float c2 = cb[dd0 + 64 + e], s2 = sb[dd0 + 64 + e];
    float x1 = bf2f((unsigned short)a[e]), x2 = bf2f((unsigned short)b8[e]);
    o1[e] = (short)f2bf(x1 * c1 - x2 * s1);
    o2[e] = (short)f2bf(x2 * c2 + x1 * s2);
  }
  *(s16x8*)p1 = o1;
  *(s16x8*)(p1 + 64) = o2;
}

// ---------------- C/S partials (8 t-splits): Cp[sp,b,d,j] = sum_{t in sp} cos*hs ----------------
__global__ __launch_bounds__(256) void cs_kernel(const float* __restrict__ hs,
                                                 const float* __restrict__ cosp,
                                                 const float* __restrict__ sinp,
                                                 float* __restrict__ Cp, float* __restrict__ Sp) {
  __shared__ __align__(16) float hsL[32][128];
  __shared__ __align__(16) float csL[32][32];
  __shared__ __align__(16) float snL[32][32];
  const int tid = threadIdx.x;
  const int j0 = blockIdx.x * 128, d0 = blockIdx.y * 32;
  const int b = blockIdx.z >> 3, sp = blockIdx.z & 7;
  const int dq = (tid & 7) * 4;
  const int jq = (tid >> 3) * 4;
  float4 aC[4], aS[4];
#pragma unroll
  for (int a = 0; a < 4; ++a) {
    aC[a] = make_float4(0.f, 0.f, 0.f, 0.f);
    aS[a] = make_float4(0.f, 0.f, 0.f, 0.f);
  }
  const int csrow = tid >> 3, csc4 = tid & 7;
  for (int tile = 0; tile < 8; ++tile) {
    int t0 = sp * 256 + tile * 32;
    const float4* hs4 = (const float4*)(hs + ((size_t)b * T_ + t0) * D_ + j0);
#pragma unroll
    for (int r = 0; r < 4; ++r) {
      int i = tid + r * 256;
      int row = i >> 5, c4 = i & 31;
      *(float4*)&hsL[row][c4 * 4] = hs4[(size_t)row * (D_ / 4) + c4];
    }
    const float4* cp4 = (const float4*)(cosp + ((size_t)b * T_ + t0) * DH_ + d0);
    const float4* sp4 = (const float4*)(sinp + ((size_t)b * T_ + t0) * DH_ + d0);
    *(float4*)&csL[csrow][csc4 * 4] = cp4[(size_t)csrow * (DH_ / 4) + csc4];
    *(float4*)&snL[csrow][csc4 * 4] = sp4[(size_t)csrow * (DH_ / 4) + csc4];
    __syncthreads();
#pragma unroll 8
    for (int tt = 0; tt < 32; ++tt) {
      float4 cv = *(const float4*)&csL[tt][dq];
      float4 sv = *(const float4*)&snL[tt][dq];
      float4 hv = *(const float4*)&hsL[tt][jq];
      float ca[4] = {cv.x, cv.y, cv.z, cv.w};
      float sa[4] = {sv.x, sv.y, sv.z, sv.w};
#pragma unroll
      for (int a = 0; a < 4; ++a) {
        aC[a].x += ca[a] * hv.x; aC[a].y += ca[a] * hv.y;
        aC[a].z += ca[a] * hv.z; aC[a].w += ca[a] * hv.w;
        aS[a].x += sa[a] * hv.x; aS[a].y += sa[a] * hv.y;
        aS[a].z += sa[a] * hv.z; aS[a].w += sa[a] * hv.w;
      }
    }
    __syncthreads();
  }
#pragma unroll
  for (int a = 0; a < 4; ++a) {
    size_t o = ((size_t)(sp * B_ + b) * DH_ + d0 + dq + a) * D_ + j0 + jq;
    *(float4*)&Cp[o] = aC[a];
    *(float4*)&Sp[o] = aS[a];
  }
}

// ---------------- reduce 8 partials -> Cr/Sr ----------------
__global__ __launch_bounds__(256) void reduce_cs_kernel(const float4* __restrict__ Cp,
                                                        const float4* __restrict__ Sp,
                                                        float4* __restrict__ Cr,
                                                        float4* __restrict__ Sr) {
  int i = blockIdx.x * 256 + threadIdx.x;   // over B*DH*D/4 = 262144
  const int str = (B_ * DH_ * D_) / 4;
  float4 c = Cp[i], s = Sp[i];
#pragma unroll
  for (int p = 1; p < 8; ++p) {
    float4 cp = Cp[i + (size_t)p * str], sq = Sp[i + (size_t)p * str];
    c.x += cp.x; c.y += cp.y; c.z += cp.z; c.w += cp.w;
    s.x += sq.x; s.y += sq.y; s.z += sq.z; s.w += sq.w;
  }
  Cr[i] = c; Sr[i] = s;
}

// ---------------- q_chunk[b,h,d] from reduced C/S (exact fp32) ----------------
__global__ __launch_bounds__(256) void qchunk_kernel(const float* __restrict__ Wq,
                                                     const float* __restrict__ Cr,
                                                     const float* __restrict__ Sr,
                                                     float* __restrict__ qc) {
  int gid = blockIdx.x * 256 + threadIdx.x;
  int wid = gid >> 6, lane = gid & 63;
  int b = wid >> 11, rem = wid & 2047;
  int h = rem >> 7, d = rem & 127;
  const float* w1 = Wq + (size_t)(h * DH_ + d) * D_;
  int dp = (d < 64) ? d + 64 : d - 64;
  float sgn = (d < 64) ? -1.f : 1.f;
  const float* w2 = Wq + (size_t)(h * DH_ + dp) * D_;
  const float* crow = Cr + ((size_t)b * DH_ + d) * D_;
  const float* srow = Sr + ((size_t)b * DH_ + d) * D_;
  float a1 = 0.f, a2 = 0.f;
  for (int j = lane; j < D_; j += 64) { a1 += w1[j] * crow[j]; a2 += w2[j] * srow[j]; }
#pragma unroll
  for (int off = 1; off < 64; off <<= 1) { a1 += __shfl_xor(a1, off); a2 += __shfl_xor(a2, off); }
  if (lane == 0) qc[wid] = (a1 + sgn * a2) * (1.f / (float)T_);
}

// ---------------- z[b,h,j] = sum_d qc[b,h,d] * Wk[kvh*128+d][j]  (fp32 exact) ----------------
__global__ __launch_bounds__(256) void zk_kernel(const float* __restrict__ qc,
                                                 const float* __restrict__ Wk,
                                                 float* __restrict__ z) {
  int j = blockIdx.x * 256 + threadIdx.x;
  int h = blockIdx.y, b = blockIdx.z;
  int kvh = h >> 1;
  const float* qcl = qc + ((size_t)b * H_ + h) * DH_;
  const float* wb = Wk + (size_t)kvh * DH_ * D_ + j;
  float acc = 0.f;
#pragma unroll 8
  for (int d = 0; d < 128; ++d) acc += qcl[d] * wb[(size_t)d * D_];
  z[((size_t)b * H_ + h) * D_ + j] = acc;
}

// ---------------- sim[b,h,n] = kScale * z[b,h,:] . mem[b,n,:] ----------------
__global__ __launch_bounds__(256) void sim_kernel(const float* __restrict__ z,
                                                  const float* __restrict__ mem,
                                                  float* __restrict__ sim) {
  __shared__ float4 mL[16 * 512];   // 128 KB, XOR-swizzled rows
  int tid = threadIdx.x;
  int n0 = blockIdx.x * 16, b = blockIdx.y;
  const float4* mem4 = (const float4*)(mem + (size_t)b * NMEM * D_);
#pragma unroll
  for (int c = 0; c < 32; ++c) {
    int i = tid + c * 256;
    int r = i >> 9, j4 = i & 511;
    mL[r * 512 + (j4 ^ (r & 7))] = mem4[(size_t)(n0 + r) * 512 + j4];
  }
  __syncthreads();
  int h = tid >> 4, n = tid & 15;
  const float4* zr = (const float4*)(z + ((size_t)b * H_ + h) * D_);
  float acc = 0.f;
  for (int j4 = 0; j4 < 512; ++j4) {
    float4 zz = zr[j4];
    float4 mm = mL[n * 512 + (j4 ^ (n & 7))];
    acc += zz.x * mm.x + zz.y * mm.y + zz.z * mm.z + zz.w * mm.w;
  }
  sim[((size_t)b * H_ + h) * NMEM + n0 + n] = acc * kScale;
}

// ---------------- top-8 per (b,h) (ties -> lowest index, matching lax.top_k) ----------------
__global__ __launch_bounds__(256) void topk_kernel(const float* __restrict__ sim,
                                                   int* __restrict__ idx) {
  __shared__ float sL[1024];
  __shared__ float rv[256];
  __shared__ int ri[256];
  int tid = threadIdx.x;
  int h = blockIdx.x, b = blockIdx.y;
  const float* sp = sim + ((size_t)b * H_ + h) * NMEM;
#pragma unroll
  for (int r = 0; r < 4; ++r) sL[tid + r * 256] = sp[tid + r * 256];
  __syncthreads();
  for (int kk = 0; kk < 8; ++kk) {
    float bv = -INFINITY; int bi = 0x7fffffff;
#pragma unroll
    for (int r = 0; r < 4; ++r) {
      int i = tid + r * 256;
      float v = sL[i];
      if (v > bv || (v == bv && i < bi)) { bv = v; bi = i; }
    }
    rv[tid] = bv; ri[tid] = bi;
    __syncthreads();
    for (int s = 128; s > 0; s >>= 1) {
      if (tid < s) {
        float v2 = rv[tid + s]; int i2 = ri[tid + s];
        if (v2 > rv[tid] || (v2 == rv[tid] && i2 < ri[tid])) { rv[tid] = v2; ri[tid] = i2; }
      }
      __syncthreads();
    }
    if (tid == 0) { idx[((size_t)b * H_ + h) * KSEL + kk] = ri[0]; sL[ri[0]] = -INFINITY; }
    __syncthreads();
  }
}

// ---------------- memory-branch attention: gather K/V rows from kvmem (bf16) ----------------
__global__ __launch_bounds__(256) void memattn_kernel(const unsigned short* __restrict__ qbf,
                                                      const unsigned short* __restrict__ kvmem,
                                                      const int* __restrict__ idx,
                                                      unsigned short* __restrict__ omem) {
  __shared__ float kl[8][128];
  __shared__ float vl[8][128];
  __shared__ int selL[8];
  int tid = threadIdx.x;
  int b = blockIdx.z, h = blockIdx.y, t = blockIdx.x * 256 + tid;
  int kvh = h >> 1;
  if (tid < 8) selL[tid] = idx[((size_t)b * H_ + h) * KSEL + tid];
  __syncthreads();
  {
    int r = tid >> 5, c4 = (tid & 31) * 4;
    size_t rb = ((size_t)b * NMEM + selL[r]) * (size_t)KVSTR;
    ushort4 k4 = *(const ushort4*)(kvmem + rb + kvh * DH_ + c4);
    ushort4 v4 = *(const ushort4*)(kvmem + rb + KV_ * DH_ + kvh * DH_ + c4);
    kl[r][c4 + 0] = bf2f(k4.x); kl[r][c4 + 1] = bf2f(k4.y);
    kl[r][c4 + 2] = bf2f(k4.z); kl[r][c4 + 3] = bf2f(k4.w);
    vl[r][c4 + 0] = bf2f(v4.x); vl[r][c4 + 1] = bf2f(v4.y);
    vl[r][c4 + 2] = bf2f(v4.z); vl[r][c4 + 3] = bf2f(v4.w);
  }
  __syncthreads();
  float sc[8] = {0.f,0.f,0.f,0.f,0.f,0.f,0.f,0.f};
  const unsigned short* qr = qbf + (size_t)(b * T_ + t) * QKVSTR + h * DH_;
  for (int c = 0; c < 4; ++c) {
    const s16x8* qp = (const s16x8*)(qr + c * 32);
#pragma unroll
    for (int u = 0; u < 4; ++u) {
      s16x8 q8 = qp[u];
#pragma unroll
      for (int e = 0; e < 8; ++e) {
        float qv = bf2f((unsigned short)q8[e]);
        int d = c * 32 + u * 8 + e;
#pragma unroll
        for (int kk = 0; kk < 8; ++kk) sc[kk] += qv * kl[kk][d];
      }
    }
  }
  float sm[8], mx = -INFINITY;
#pragma unroll
  for (int kk = 0; kk < 8; ++kk) { sm[kk] = sc[kk] * kScale; mx = fmaxf(mx, sm[kk]); }
  float sum = 0.f;
#pragma unroll
  for (int kk = 0; kk < 8; ++kk) { sm[kk] = __expf(sm[kk] - mx); sum += sm[kk]; }
  float inv = 1.f / sum;
#pragma unroll
  for (int kk = 0; kk < 8; ++kk) sm[kk] *= inv;
  unsigned short* orow = omem + (size_t)(b * T_ + t) * D_ + h * DH_;
  for (int d = 0; d < 128; d += 4) {
    float o0 = 0.f, o1 = 0.f, o2 = 0.f, o3 = 0.f;
#pragma unroll
    for (int kk = 0; kk < 8; ++kk) {
      float w = sm[kk];
      o0 += w * vl[kk][d + 0];
      o1 += w * vl[kk][d + 1];
      o2 += w * vl[kk][d + 2];
      o3 += w * vl[kk][d + 3];
    }
    uint2 pk;
    pk.x = (unsigned)f2bf(o0) | ((unsigned)f2bf(o1) << 16);
    pk.y = (unsigned)f2bf(o2) | ((unsigned)f2bf(o3) << 16);
    *(uint2*)(orow + d) = pk;
  }
}

// ---------------- gate: g = sigmoid(hs . Wg + bg) ----------------
__global__ __launch_bounds__(256) void gate_kernel(const float* __restrict__ hs,
                                                   const float* __restrict__ Wg,
                                                   const float* __restrict__ bg,
                                                   float* __restrict__ g) {
  int gid = blockIdx.x * 256 + threadIdx.x;
  int row = gid >> 6, lane = gid & 63;
  const float4* hr = (const float4*)(hs + (size_t)row * D_);
  const float4* wg4 = (const float4*)Wg;
  float acc = 0.f;
#pragma unroll
  for (int it = 0; it < 8; ++it) {
    float4 hv = hr[lane + it * 64], wv = wg4[lane + it * 64];
    acc += hv.x * wv.x + hv.y * wv.y + hv.z * wv.z + hv.w * wv.w;
  }
#pragma unroll
  for (int off = 1; off < 64; off <<= 1) acc += __shfl_xor(acc, off);
  if (lane == 0) g[row] = 1.f / (1.f + __expf(-(acc + bg[0])));
}

// ---------------- local sliding-window attention (flash, per-wave 16 rows) ----------------
// q/k/v all live in qkv buffer, row stride QKVSTR.
__global__ __launch_bounds__(256) void localattn_kernel(const unsigned short* __restrict__ qbf,
                                                        const unsigned short* __restrict__ kbf,
                                                        const unsigned short* __restrict__ vbf,
                                                        unsigned short* __restrict__ olocal) {
  __shared__ __align__(16) unsigned short pl[4][16][40];
  const int tid = threadIdx.x;
  const int w = tid >> 6, lane = tid & 63;
  const int tb = blockIdx.x * 64;
  const int h = blockIdx.y, b = blockIdx.z;
  const int kvh = h >> 1;
  const int t0 = tb + w * 16;
  const int l15 = lane & 15, lg = lane >> 4;

  s16x8 qf[4];
  {
    const unsigned short* qb = qbf + ((size_t)(b * T_ + t0 + l15) * QKVSTR) + h * DH_ + lg * 8;
#pragma unroll
    for (int kb = 0; kb < 4; ++kb) qf[kb] = *(const s16x8*)(qb + kb * 32);
  }
  f32x4 of[8];
#pragma unroll
  for (int nb = 0; nb < 8; ++nb) of[nb] = fzero4();
  float m_r[4] = {-INFINITY, -INFINITY, -INFINITY, -INFINITY};
  float l_r[4] = {0.f, 0.f, 0.f, 0.f};

  int sstart = t0 - (WWIN - 1);
  if (sstart < 0) sstart = 0;
  sstart &= ~31;
  for (int s0 = sstart; s0 <= t0 + 15; s0 += 32) {
    f32x4 sc[2];
    sc[0] = fzero4(); sc[1] = fzero4();
    const unsigned short* kb0 = kbf + ((size_t)(b * T_ + s0 + l15) * QKVSTR) + kvh * DH_ + lg * 8;
#pragma unroll
    for (int cb = 0; cb < 2; ++cb) {
#pragma unroll
      for (int kb = 0; kb < 4; ++kb) {
        s16x8 kf = *(const s16x8*)(kb0 + (size_t)cb * 16 * QKVSTR + kb * 32);
        sc[cb] = __builtin_amdgcn_mfma_f32_16x16x32_bf16(qf[kb], kf, sc[cb], 0, 0, 0);
      }
    }
    float pv[2][4];
#pragma unroll
    for (int j = 0; j < 4; ++j) {
      int t = t0 + lg * 4 + j;
      int s_a = s0 + l15, s_b = s_a + 16;
      float va = sc[0][j] * kScale;
      float vb = sc[1][j] * kScale;
      va = (s_a <= t && s_a + (WWIN - 1) >= t) ? va : -INFINITY;
      vb = (s_b <= t && s_b + (WWIN - 1) >= t) ? vb : -INFINITY;
      float mx = fmaxf(va, vb);
#pragma unroll
      for (int off = 1; off < 16; off <<= 1) mx = fmaxf(mx, __shfl_xor(mx, off));
      float mn = fmaxf(m_r[j], mx);
      float alpha, pa, pb;
      if (mn == -INFINITY) { alpha = 1.f; pa = 0.f; pb = 0.f; }
      else {
        alpha = __expf(m_r[j] - mn);
        pa = __expf(va - mn);
        pb = __expf(vb - mn);
      }
      m_r[j] = mn;
      float rs = pa + pb;
#pragma unroll
      for (int off = 1; off < 16; off <<= 1) rs += __shfl_xor(rs, off);
      l_r[j] = l_r[j] * alpha + rs;
#pragma unroll
      for (int nb = 0; nb < 8; ++nb) of[nb][j] *= alpha;
      pv[0][j] = pa; pv[1][j] = pb;
    }
#pragma unroll
    for (int cb = 0; cb < 2; ++cb)
#pragma unroll
      for (int j = 0; j < 4; ++j)
        pl[w][lg * 4 + j][cb * 16 + l15] = f2bf(pv[cb][j]);
    asm volatile("s_waitcnt lgkmcnt(0)" ::: "memory");
    __builtin_amdgcn_sched_barrier(0);
    s16x8 pa8 = *(const s16x8*)&pl[w][l15][lg * 8];
    const unsigned short* vb0 = vbf + ((size_t)(b * T_ + s0 + lg * 8) * QKVSTR) + kvh * DH_ + l15;
#pragma unroll
    for (int nb = 0; nb < 8; ++nb) {
      s16x8 vf;
#pragma unroll
      for (int jj = 0; jj < 8; ++jj) vf[jj] = (short)vb0[(size_t)jj * QKVSTR + nb * 16];
      of[nb] = __builtin_amdgcn_mfma_f32_16x16x32_bf16(pa8, vf, of[nb], 0, 0, 0);
    }
  }
  float inv[4];
#pragma unroll
  for (int j = 0; j < 4; ++j) inv[j] = 1.f / l_r[j];
#pragma unroll
  for (int nb = 0; nb < 8; ++nb)
#pragma unroll
    for (int j = 0; j < 4; ++j) {
      int t = t0 + lg * 4 + j;
      olocal[(size_t)(b * T_ + t) * QKVSTR + h * DH_ + nb * 16 + l15] = f2bf(of[nb][j] * inv[j]);
    }
}

// ---------------- host launcher ----------------
extern "C" void kernel_launch(void* const* d_in, const int* in_sizes, int n_in,
                              void* d_out, int out_size, void* d_ws, size_t ws_size,
                              hipStream_t stream) {
  const float* hs   = (const float*)d_in[0];
  const float* cosp = (const float*)d_in[1];
  const float* sinp = (const float*)d_in[2];
  const float* mem  = (const float*)d_in[3];
  const float* Wq   = (const float*)d_in[4];
  const float* Wk   = (const float*)d_in[5];
  const float* Wv   = (const float*)d_in[6];
  const float* Wo   = (const float*)d_in[7];
  const float* Wg   = (const float*)d_in[8];
  const float* bg   = (const float*)d_in[9];
  float* out = (float*)d_out;

  char* p = (char*)d_ws;
  auto alloc = [&](size_t bytes) { char* r = p; p += (bytes + 255) & ~(size_t)255; return r; };
  // small buffers first, then big. Total ~84.4 MB.
  float* qc     = (float*)alloc((size_t)B_ * H_ * DH_ * 4);
  float* gbuf   = (float*)alloc((size_t)BT * 4);
  float* zbuf   = (float*)alloc((size_t)B_ * H_ * D_ * 4);
  float* simbuf = (float*)alloc((size_t)B_ * H_ * NMEM * 4);
  int*   idxbuf = (int*)alloc((size_t)B_ * H_ * KSEL * 4);
  unsigned short* hs_bf   = (unsigned short*)alloc((size_t)BT * D_ * 2);       // -> o_mem bf16 later
  unsigned short* qkv_raw = (unsigned short*)alloc((size_t)BT * QKVSTR * 2);   // q|k|v merged; q -> o_local in place
  unsigned short* wbig    = (unsigned short*)alloc((size_t)2 * D_ * D_ * 2);   // Wq|Wk|Wv stack -> Wo reuses head
  unsigned short* mem_bf  = (unsigned short*)alloc((size_t)B_ * NMEM * D_ * 2); // -> Cr/Sr later
  unsigned short* kvmem   = (unsigned short*)alloc((size_t)B_ * NMEM * KVSTR * 2);

  // C/S partials live in d_out (33.55 MB, exact fit; fully rewritten by final GEMM)
  float* Cp = (float*)d_out;
  float* Sp = Cp + (size_t)8 * B_ * DH_ * D_;
  float* Cr = (float*)mem_bf;            // after kvmem-gemm, mem_bf is dead (8.39 MB exact)
  float* Sr = Cr + (size_t)B_ * DH_ * D_;
  unsigned short* omem_bf = hs_bf;       // after merged gemm, hs_bf is dead until memattn writes it

  // 1) conversions + merged QKV projection (bf16 MFMA)
  conv_kernel<<<(BT * D_ / 4 + 255) / 256, 256, 0, stream>>>(hs, hs_bf, BT * D_);
  conv_kernel<<<(D_ * D_ / 4 + 255) / 256, 256, 0, stream>>>(Wq, wbig, D_ * D_);
  conv_kernel<<<(KV_ * DH_ * D_ / 4 + 255) / 256, 256, 0, stream>>>(Wk, wbig + (size_t)D_ * D_, KV_ * DH_ * D_);
  conv_kernel<<<(KV_ * DH_ * D_ / 4 + 255) / 256, 256, 0, stream>>>(Wv, wbig + (size_t)D_ * D_ + (size_t)KV_ * DH_ * D_, KV_ * DH_ * D_);
  gemm_bt<0><<<dim3(QKVSTR / 128, BT / 128), 256, 0, stream>>>(hs_bf, wbig, QKVSTR, D_, D_, QKVSTR, qkv_raw, nullptr, nullptr, nullptr);
  // kvmem = mem_bf @ (Wk|Wv)^T  (values only; selection stays fp32)
  conv_kernel<<<(B_ * NMEM * D_ / 4 + 255) / 256, 256, 0, stream>>>(mem, mem_bf, B_ * NMEM * D_);
  gemm_bt<0><<<dim3(KVSTR / 128, (B_ * NMEM) / 128), 256, 0, stream>>>(mem_bf, wbig + (size_t)D_ * D_, KVSTR, D_, D_, KVSTR, kvmem, nullptr, nullptr, nullptr);

  // 2) in-place RoPE (q section: 1024 pairs/row; k section: 512 pairs/row)
  rope_ip_kernel<<<(BT * D_ / 16 + 255) / 256, 256, 0, stream>>>(qkv_raw, cosp, sinp, 10, QKVSTR, BT * D_ / 16);
  rope_ip_kernel<<<(BT * KV_ * DH_ / 16 + 255) / 256, 256, 0, stream>>>(qkv_raw + D_, cosp, sinp, 9, QKVSTR, BT * KV_ * DH_ / 16);

  // 3) exact-fp32 selection path (Cp/Sp scratch in d_out; Cr/Sr in dead mem_bf)
  cs_kernel<<<dim3(D_ / 128, DH_ / 32, B_ * 8), 256, 0, stream>>>(hs, cosp, sinp, Cp, Sp);
  reduce_cs_kernel<<<(B_ * DH_ * D_ / 4) / 256, 256, 0, stream>>>((const float4*)Cp, (const float4*)Sp, (float4*)Cr, (float4*)Sr);
  qchunk_kernel<<<(B_ * H_ * DH_) / 4, 256, 0, stream>>>(Wq, Cr, Sr, qc);
  zk_kernel<<<dim3(D_ / 256, H_, B_), 256, 0, stream>>>(qc, Wk, zbuf);
  sim_kernel<<<dim3(NMEM / 16, B_), 256, 0, stream>>>(zbuf, mem, simbuf);
  topk_kernel<<<dim3(H_, B_), 256, 0, stream>>>(simbuf, idxbuf);

  // 4) memory-branch attention (gathers K/V from kvmem) -> o_mem bf16 (reuses hs_bf)
  memattn_kernel<<<dim3(T_ / 256, H_, B_), 256, 0, stream>>>(qkv_raw, kvmem, idxbuf, omem_bf);

  // 5) gate
  gate_kernel<<<BT / 4, 256, 0, stream>>>(hs, Wg, bg, gbuf);

  // 6) local sliding-window attention (writes o_local in place over q section)
  localattn_kernel<<<dim3(T_ / 64, H_, B_), 256, 0, stream>>>(qkv_raw, qkv_raw + D_, qkv_raw + D_ + KV_ * DH_, qkv_raw);

  // 7) Wo projection + final combine (d_out pure write; overwrites Cp/Sp scratch)
  conv_kernel<<<(D_ * D_ / 4 + 255) / 256, 256, 0, stream>>>(Wo, wbig, D_ * D_);
  gemm_bt<1><<<dim3(D_ / 128, BT / 128), 256, 0, stream>>>(qkv_raw, wbig, D_, D_, QKVSTR, D_, nullptr, gbuf, omem_bf, out);
}

// Round 7
// 462.756 us; speedup vs baseline: 2.1890x; 1.0817x over previous
//
#include <hip/hip_runtime.h>
#include <stdint.h>

#define B_   2
#define T_   2048
#define D_   2048
#define H_   16
#define KV_  8
#define DH_  128
#define NMEM 1024
#define WWIN 256
#define KSEL 8
#define BT   (B_*T_)
#define KVSTR 2048    // kvmem row stride (elements)
#define QKVSTR 4096   // merged qkv row stride (elements)

__constant__ const float kScale = 0.08838834764831845f; // DH^-0.5

typedef __attribute__((ext_vector_type(8))) short s16x8;
typedef __attribute__((ext_vector_type(4))) float f32x4;

__device__ inline unsigned short f2bf(float f) {
  union { float f; unsigned int u; } c; c.f = f;
  unsigned int u = c.u;
  unsigned int r = u + 0x7fffu + ((u >> 16) & 1u);
  return (unsigned short)(r >> 16);
}
__device__ inline float bf2f(unsigned short v) {
  union { unsigned int u; float f; } c; c.u = ((unsigned int)v) << 16;
  return c.f;
}
__device__ inline f32x4 fzero4() { f32x4 v; v[0]=0.f; v[1]=0.f; v[2]=0.f; v[3]=0.f; return v; }

// ---------------- fp32 -> bf16 conversion (float4 wide) ----------------
__global__ __launch_bounds__(256) void conv_kernel(const float* __restrict__ src,
                                                   unsigned short* __restrict__ dst, int n) {
  int i = blockIdx.x * 256 + threadIdx.x;
  if (i * 4 >= n) return;
  float4 v = ((const float4*)src)[i];
  uint2 o;
  o.x = (unsigned)f2bf(v.x) | ((unsigned)f2bf(v.y) << 16);
  o.y = (unsigned)f2bf(v.z) | ((unsigned)f2bf(v.w) << 16);
  ((uint2*)dst)[i] = o;
}

// ================= 256x256 8-phase GEMM (T2+T3+T4+T5) =================
// C[M,N] = A[M,K](lda) @ B[N,K]^T, C stride ldc. 512 threads, 128KB LDS.
// MODE 0: bf16 C.  MODE 1: dout = g[row]*acc + (1-g[row])*bf2f(omem)
#define AOFF(buf, half) ((buf)*32768 + (half)*16384)
#define BOFF(buf, half) (65536 + (buf)*32768 + (half)*16384)

#define PH_MFMA(P, BF) \
  { \
    _Pragma("unroll") \
    for (int mi = 0; mi < 2; ++mi) { \
      _Pragma("unroll") \
      for (int ni = 0; ni < 4; ++ni) { \
        acc[P][mi][ni] = __builtin_amdgcn_mfma_f32_16x16x32_bf16(af[mi][0], BF[ni][0], acc[P][mi][ni], 0, 0, 0); \
        acc[P][mi][ni] = __builtin_amdgcn_mfma_f32_16x16x32_bf16(af[mi][1], BF[ni][1], acc[P][mi][ni], 0, 0, 0); \
      } \
    } \
  }

template<int MODE>
__global__ __launch_bounds__(512, 2) void gemm256(const unsigned short* __restrict__ A,
                                                  const unsigned short* __restrict__ Bw,
                                                  int N, int K, int lda, int ldc,
                                                  unsigned short* __restrict__ Cb,
                                                  const float* __restrict__ g,
                                                  const unsigned short* __restrict__ omem,
                                                  float* __restrict__ dout) {
  __shared__ __align__(16) char lds[131072];
  const int tid = threadIdx.x;
  const int wv = tid >> 6, lane = tid & 63;
  const int l15 = lane & 15, lg = lane >> 4;
  const int wr = wv >> 1, wc = wv & 1;   // 4 row-slices x 2 col-halves
  // XCD-aware bijective swizzle (nwg % 8 == 0)
  const int gx = gridDim.x;
  const int nwg = gx * gridDim.y;
  const int flat = blockIdx.y * gx + blockIdx.x;
  const int chunk = nwg >> 3;
  const int wg = (flat & 7) * chunk + (flat >> 3);
  const int bx = wg % gx, by = wg / gx;
  const int m0 = by * 256, n0 = bx * 256;
  const int NT = K >> 6;

  // stage one half-tile (128 rows x 64 cols bf16 = 16KB): 2 gld_lds/thread.
  // LDS linear [row][8 chunks of 16B]; global chunk cg = slot ^ (row&7)
  // (pre-swizzled source so swizzled ds_read is conflict-free).
  auto stage_half = [&](const unsigned short* base, int stride, int row0, int koff, int ldsoff) {
#pragma unroll
    for (int ld = 0; ld < 2; ++ld) {
      int s = ld * 512 + tid;
      int row = s >> 3, cs = s & 7;
      int cg = cs ^ (row & 7);
      const unsigned short* src = base + (size_t)(row0 + row) * stride + koff + cg * 8;
      __builtin_amdgcn_global_load_lds((const __attribute__((address_space(1))) void*)src,
          (__attribute__((address_space(3))) void*)(lds + ldsoff + ld * 8192 + wv * 1024), 16, 0, 0);
    }
  };
  auto rdA = [&](int buf, int half, int mi, int kk) -> s16x8 {
    int r = wr * 32 + mi * 16 + l15;
    int slot = (kk * 4 + lg) ^ (r & 7);
    return *(const s16x8*)(lds + AOFF(buf, half) + r * 128 + slot * 16);
  };
  auto rdB = [&](int buf, int half, int ni, int kk) -> s16x8 {
    int r = wc * 64 + ni * 16 + l15;
    int slot = (kk * 4 + lg) ^ (r & 7);
    return *(const s16x8*)(lds + BOFF(buf, half) + r * 128 + slot * 16);
  };

  f32x4 acc[4][2][4];
#pragma unroll
  for (int p = 0; p < 4; ++p)
#pragma unroll
    for (int mi = 0; mi < 2; ++mi)
#pragma unroll
      for (int ni = 0; ni < 4; ++ni) acc[p][mi][ni] = fzero4();

  // prologue: T0 full (buf0), T1 {A0,B0,A1} (buf1); B1 of T1 staged at t=0 p0.
  stage_half(A,  lda, m0,       0,  AOFF(0, 0));
  stage_half(Bw, K,   n0,       0,  BOFF(0, 0));
  stage_half(A,  lda, m0 + 128, 0,  AOFF(0, 1));
  stage_half(Bw, K,   n0 + 128, 0,  BOFF(0, 1));
  stage_half(A,  lda, m0,       64, AOFF(1, 0));
  stage_half(Bw, K,   n0,       64, BOFF(1, 0));
  stage_half(A,  lda, m0 + 128, 64, AOFF(1, 1));
  asm volatile("s_waitcnt vmcnt(6)" ::: "memory");   // T0 landed
  __builtin_amdgcn_s_barrier();

  int cur = 0;
  for (int t = 0; t < NT; ++t, cur ^= 1) {
    const int nxt = cur ^ 1;
    s16x8 af[2][2], b0f[4][2], b1f[4][2];
    // ---- phase 0: quadrant (A0,B0); read A0+B0 frags; stage (t+1, B1) -> nxt
#pragma unroll
    for (int mi = 0; mi < 2; ++mi) {
      af[mi][0] = rdA(cur, 0, mi, 0);
      af[mi][1] = rdA(cur, 0, mi, 1);
    }
#pragma unroll
    for (int ni = 0; ni < 4; ++ni) {
      b0f[ni][0] = rdB(cur, 0, ni, 0);
      b0f[ni][1] = rdB(cur, 0, ni, 1);
    }
    if (t + 1 < NT) stage_half(Bw, K, n0 + 128, (t + 1) * 64, BOFF(nxt, 1));
    __builtin_amdgcn_sched_barrier(0);
    __builtin_amdgcn_s_barrier();
    asm volatile("s_waitcnt lgkmcnt(0)" ::: "memory");
    __builtin_amdgcn_sched_barrier(0);
    __builtin_amdgcn_s_setprio(1);
    PH_MFMA(0, b0f);
    __builtin_amdgcn_s_setprio(0);
    __builtin_amdgcn_s_barrier();
    // ---- phase 1: quadrant (A0,B1); read B1 frags; stage (t+2, A0) -> cur
#pragma unroll
    for (int ni = 0; ni < 4; ++ni) {
      b1f[ni][0] = rdB(cur, 1, ni, 0);
      b1f[ni][1] = rdB(cur, 1, ni, 1);
    }
    if (t + 2 < NT) stage_half(A, lda, m0, (t + 2) * 64, AOFF(cur, 0));
    __builtin_amdgcn_sched_barrier(0);
    __builtin_amdgcn_s_barrier();
    asm volatile("s_waitcnt lgkmcnt(0)" ::: "memory");
    __builtin_amdgcn_sched_barrier(0);
    __builtin_amdgcn_s_setprio(1);
    PH_MFMA(1, b1f);
    __builtin_amdgcn_s_setprio(0);
    __builtin_amdgcn_s_barrier();
    // ---- phase 2: quadrant (A1,B0); read A1 frags; stage (t+2, B0) -> cur
#pragma unroll
    for (int mi = 0; mi < 2; ++mi) {
      af[mi][0] = rdA(cur, 1, mi, 0);
      af[mi][1] = rdA(cur, 1, mi, 1);
    }
    if (t + 2 < NT) stage_half(Bw, K, n0, (t + 2) * 64, BOFF(cur, 0));
    __builtin_amdgcn_sched_barrier(0);
    __builtin_amdgcn_s_barrier();
    asm volatile("s_waitcnt lgkmcnt(0)" ::: "memory");
    __builtin_amdgcn_sched_barrier(0);
    __builtin_amdgcn_s_setprio(1);
    PH_MFMA(2, b0f);
    __builtin_amdgcn_s_setprio(0);
    __builtin_amdgcn_s_barrier();
    // ---- phase 3: quadrant (A1,B1); no reads; stage (t+2, A1) -> cur
    if (t + 2 < NT) stage_half(A, lda, m0 + 128, (t + 2) * 64, AOFF(cur, 1));
    __builtin_amdgcn_sched_barrier(0);
    __builtin_amdgcn_s_barrier();
    __builtin_amdgcn_s_setprio(1);
    PH_MFMA(3, b1f);
    __builtin_amdgcn_s_setprio(0);
    if (t < NT - 2) asm volatile("s_waitcnt vmcnt(6)" ::: "memory");
    else            asm volatile("s_waitcnt vmcnt(0)" ::: "memory");
    __builtin_amdgcn_s_barrier();
  }

#pragma unroll
  for (int p = 0; p < 4; ++p)
#pragma unroll
    for (int mi = 0; mi < 2; ++mi)
#pragma unroll
      for (int ni = 0; ni < 4; ++ni)
#pragma unroll
        for (int j = 0; j < 4; ++j) {
          int row_g = m0 + (p >> 1) * 128 + wr * 32 + mi * 16 + lg * 4 + j;
          int col_g = n0 + (p & 1) * 128 + wc * 64 + ni * 16 + l15;
          float v = acc[p][mi][ni][j];
          size_t o = (size_t)row_g * ldc + col_g;
          if constexpr (MODE == 0) {
            Cb[o] = f2bf(v);
          } else {
            float gv = g[row_g];
            dout[o] = gv * v + (1.f - gv) * bf2f(omem[o]);
          }
        }
}

// ---------------- bf16 GEMM 128-tile (kept for kvmem) ----------------
template<int MODE>
__global__ __launch_bounds__(256) void gemm_bt(const unsigned short* __restrict__ A,
                                               const unsigned short* __restrict__ Bw,
                                               int N, int K, int lda, int ldc,
                                               unsigned short* __restrict__ Cb,
                                               const float* __restrict__ g,
                                               const unsigned short* __restrict__ omem,
                                               float* __restrict__ dout) {
  __shared__ __align__(16) unsigned short sA[128 * 32];
  __shared__ __align__(16) unsigned short sB[128 * 32];
  const int tid = threadIdx.x;
  const int wv = tid >> 6, lane = tid & 63;
  const int gx = gridDim.x;
  const int nwg = gx * gridDim.y;
  const int flat = blockIdx.y * gx + blockIdx.x;
  const int chunk = nwg >> 3;
  const int wg = (flat & 7) * chunk + (flat >> 3);
  const int bx = wg % gx, by = wg / gx;
  const int m0 = by * 128, n0 = bx * 128;
  const int wr = wv >> 1, wc = wv & 1;
  const int l15 = lane & 15, lg = lane >> 4;
  const int rowA = tid >> 2;
  const int colB = (tid & 3) * 16; // bytes
  f32x4 acc[4][4];
#pragma unroll
  for (int mi = 0; mi < 4; ++mi)
#pragma unroll
    for (int ni = 0; ni < 4; ++ni) acc[mi][ni] = fzero4();

  char* sAc = (char*)sA;
  char* sBc = (char*)sB;
  for (int k0 = 0; k0 < K; k0 += 32) {
#pragma unroll
    for (int e = 0; e < 2; ++e) {
      const char* ga = (const char*)(A + ((size_t)(m0 + rowA + e * 64) * lda + k0)) + colB;
      __builtin_amdgcn_global_load_lds((const __attribute__((address_space(1))) void*)ga,
          (__attribute__((address_space(3))) void*)(sAc + e * 4096 + wv * 1024), 16, 0, 0);
      const char* gb = (const char*)(Bw + ((size_t)(n0 + rowA + e * 64) * K + k0)) + colB;
      __builtin_amdgcn_global_load_lds((const __attribute__((address_space(1))) void*)gb,
          (__attribute__((address_space(3))) void*)(sBc + e * 4096 + wv * 1024), 16, 0, 0);
    }
    __syncthreads();
    s16x8 af[4], bf_[4];
#pragma unroll
    for (int mi = 0; mi < 4; ++mi)
      af[mi] = *(const s16x8*)&sA[(wr * 64 + mi * 16 + l15) * 32 + lg * 8];
#pragma unroll
    for (int ni = 0; ni < 4; ++ni)
      bf_[ni] = *(const s16x8*)&sB[(wc * 64 + ni * 16 + l15) * 32 + lg * 8];
#pragma unroll
    for (int mi = 0; mi < 4; ++mi)
#pragma unroll
      for (int ni = 0; ni < 4; ++ni)
        acc[mi][ni] = __builtin_amdgcn_mfma_f32_16x16x32_bf16(af[mi], bf_[ni], acc[mi][ni], 0, 0, 0);
    __syncthreads();
  }
#pragma unroll
  for (int mi = 0; mi < 4; ++mi)
#pragma unroll
    for (int ni = 0; ni < 4; ++ni)
#pragma unroll
      for (int j = 0; j < 4; ++j) {
        int row_g = m0 + wr * 64 + mi * 16 + lg * 4 + j;
        int col_g = n0 + wc * 64 + ni * 16 + l15;
        float v = acc[mi][ni][j];
        size_t o = (size_t)row_g * ldc + col_g;
        if constexpr (MODE == 0) {
          Cb[o] = f2bf(v);
        } else {
          float gv = g[row_g];
          float om = bf2f(omem[o]);
          dout[o] = gv * v + (1.f - gv) * om;
        }
      }
}

// ---------------- in-place pairwise RoPE (bf16) ----------------
__global__ __launch_bounds__(256) void rope_ip_kernel(unsigned short* __restrict__ buf,
                                                      const float* __restrict__ cosp,
                                                      const float* __restrict__ sinp,
                                                      int logp, int stride, int nthreads) {
  int i = blockIdx.x * 256 + threadIdx.x;
  if (i >= nthreads) return;
  int pp = i * 8;
  int row = pp >> logp;
  int p0 = pp & ((1 << logp) - 1);
  int blk = p0 >> 6, dd0 = p0 & 63;
  int b = row >> 11, t = row & 2047;
  const float* cb = cosp + ((size_t)b * T_ + t) * DH_;
  const float* sb = sinp + ((size_t)b * T_ + t) * DH_;
  unsigned short* p1 = buf + (size_t)row * stride + blk * 128 + dd0;
  s16x8 a = *(s16x8*)p1;
  s16x8 b8 = *(s16x8*)(p1 + 64);
  s16x8 o1, o2;
#pragma unroll
  for (int e = 0; e < 8; ++e) {
    float c1 = cb[dd0 + e], s1 = sb[dd0 + e];
    float c2 = cb[dd0 + 64 + e], s2 = sb[dd0 + 64 + e];
    float x1 = bf2f((unsigned short)a[e]), x2 = bf2f((unsigned short)b8[e]);
    o1[e] = (short)f2bf(x1 * c1 - x2 * s1);
    o2[e] = (short)f2bf(x2 * c2 + x1 * s2);
  }
  *(s16x8*)p1 = o1;
  *(s16x8*)(p1 + 64) = o2;
}

// ---------------- C/S partials (8 t-splits) ----------------
__global__ __launch_bounds__(256) void cs_kernel(const float* __restrict__ hs,
                                                 const float* __restrict__ cosp,
                                                 const float* __restrict__ sinp,
                                                 float* __restrict__ Cp, float* __restrict__ Sp) {
  __shared__ __align__(16) float hsL[32][128];
  __shared__ __align__(16) float csL[32][32];
  __shared__ __align__(16) float snL[32][32];
  const int tid = threadIdx.x;
  const int j0 = blockIdx.x * 128, d0 = blockIdx.y * 32;
  const int b = blockIdx.z >> 3, sp = blockIdx.z & 7;
  const int dq = (tid & 7) * 4;
  const int jq = (tid >> 3) * 4;
  float4 aC[4], aS[4];
#pragma unroll
  for (int a = 0; a < 4; ++a) {
    aC[a] = make_float4(0.f, 0.f, 0.f, 0.f);
    aS[a] = make_float4(0.f, 0.f, 0.f, 0.f);
  }
  const int csrow = tid >> 3, csc4 = tid & 7;
  for (int tile = 0; tile < 8; ++tile) {
    int t0 = sp * 256 + tile * 32;
    const float4* hs4 = (const float4*)(hs + ((size_t)b * T_ + t0) * D_ + j0);
#pragma unroll
    for (int r = 0; r < 4; ++r) {
      int i = tid + r * 256;
      int row = i >> 5, c4 = i & 31;
      *(float4*)&hsL[row][c4 * 4] = hs4[(size_t)row * (D_ / 4) + c4];
    }
    const float4* cp4 = (const float4*)(cosp + ((size_t)b * T_ + t0) * DH_ + d0);
    const float4* sp4 = (const float4*)(sinp + ((size_t)b * T_ + t0) * DH_ + d0);
    *(float4*)&csL[csrow][csc4 * 4] = cp4[(size_t)csrow * (DH_ / 4) + csc4];
    *(float4*)&snL[csrow][csc4 * 4] = sp4[(size_t)csrow * (DH_ / 4) + csc4];
    __syncthreads();
#pragma unroll 8
    for (int tt = 0; tt < 32; ++tt) {
      float4 cv = *(const float4*)&csL[tt][dq];
      float4 sv = *(const float4*)&snL[tt][dq];
      float4 hv = *(const float4*)&hsL[tt][jq];
      float ca[4] = {cv.x, cv.y, cv.z, cv.w};
      float sa[4] = {sv.x, sv.y, sv.z, sv.w};
#pragma unroll
      for (int a = 0; a < 4; ++a) {
        aC[a].x += ca[a] * hv.x; aC[a].y += ca[a] * hv.y;
        aC[a].z += ca[a] * hv.z; aC[a].w += ca[a] * hv.w;
        aS[a].x += sa[a] * hv.x; aS[a].y += sa[a] * hv.y;
        aS[a].z += sa[a] * hv.z; aS[a].w += sa[a] * hv.w;
      }
    }
    __syncthreads();
  }
#pragma unroll
  for (int a = 0; a < 4; ++a) {
    size_t o = ((size_t)(sp * B_ + b) * DH_ + d0 + dq + a) * D_ + j0 + jq;
    *(float4*)&Cp[o] = aC[a];
    *(float4*)&Sp[o] = aS[a];
  }
}

// ---------------- reduce 8 partials -> Cr/Sr ----------------
__global__ __launch_bounds__(256) void reduce_cs_kernel(const float4* __restrict__ Cp,
                                                        const float4* __restrict__ Sp,
                                                        float4* __restrict__ Cr,
                                                        float4* __restrict__ Sr) {
  int i = blockIdx.x * 256 + threadIdx.x;
  const int str = (B_ * DH_ * D_) / 4;
  float4 c = Cp[i], s = Sp[i];
#pragma unroll
  for (int p = 1; p < 8; ++p) {
    float4 cp = Cp[i + (size_t)p * str], sq = Sp[i + (size_t)p * str];
    c.x += cp.x; c.y += cp.y; c.z += cp.z; c.w += cp.w;
    s.x += sq.x; s.y += sq.y; s.z += sq.z; s.w += sq.w;
  }
  Cr[i] = c; Sr[i] = s;
}

// ---------------- q_chunk[b,h,d] from reduced C/S (exact fp32) ----------------
__global__ __launch_bounds__(256) void qchunk_kernel(const float* __restrict__ Wq,
                                                     const float* __restrict__ Cr,
                                                     const float* __restrict__ Sr,
                                                     float* __restrict__ qc) {
  int gid = blockIdx.x * 256 + threadIdx.x;
  int wid = gid >> 6, lane = gid & 63;
  int b = wid >> 11, rem = wid & 2047;
  int h = rem >> 7, d = rem & 127;
  const float* w1 = Wq + (size_t)(h * DH_ + d) * D_;
  int dp = (d < 64) ? d + 64 : d - 64;
  float sgn = (d < 64) ? -1.f : 1.f;
  const float* w2 = Wq + (size_t)(h * DH_ + dp) * D_;
  const float* crow = Cr + ((size_t)b * DH_ + d) * D_;
  const float* srow = Sr + ((size_t)b * DH_ + d) * D_;
  float a1 = 0.f, a2 = 0.f;
  for (int j = lane; j < D_; j += 64) { a1 += w1[j] * crow[j]; a2 += w2[j] * srow[j]; }
#pragma unroll
  for (int off = 1; off < 64; off <<= 1) { a1 += __shfl_xor(a1, off); a2 += __shfl_xor(a2, off); }
  if (lane == 0) qc[wid] = (a1 + sgn * a2) * (1.f / (float)T_);
}

// ---------------- z[b,h,j] = sum_d qc[b,h,d] * Wk[kvh*128+d][j] ----------------
__global__ __launch_bounds__(256) void zk_kernel(const float* __restrict__ qc,
                                                 const float* __restrict__ Wk,
                                                 float* __restrict__ z) {
  int j = blockIdx.x * 256 + threadIdx.x;
  int h = blockIdx.y, b = blockIdx.z;
  int kvh = h >> 1;
  const float* qcl = qc + ((size_t)b * H_ + h) * DH_;
  const float* wb = Wk + (size_t)kvh * DH_ * D_ + j;
  float acc = 0.f;
#pragma unroll 8
  for (int d = 0; d < 128; ++d) acc += qcl[d] * wb[(size_t)d * D_];
  z[((size_t)b * H_ + h) * D_ + j] = acc;
}

// ---------------- sim[b,h,n] = kScale * z[b,h,:] . mem[b,n,:] ----------------
__global__ __launch_bounds__(256) void sim_kernel(const float* __restrict__ z,
                                                  const float* __restrict__ mem,
                                                  float* __restrict__ sim) {
  __shared__ float4 mL[16 * 512];
  int tid = threadIdx.x;
  int n0 = blockIdx.x * 16, b = blockIdx.y;
  const float4* mem4 = (const float4*)(mem + (size_t)b * NMEM * D_);
#pragma unroll
  for (int c = 0; c < 32; ++c) {
    int i = tid + c * 256;
    int r = i >> 9, j4 = i & 511;
    mL[r * 512 + (j4 ^ (r & 7))] = mem4[(size_t)(n0 + r) * 512 + j4];
  }
  __syncthreads();
  int h = tid >> 4, n = tid & 15;
  const float4* zr = (const float4*)(z + ((size_t)b * H_ + h) * D_);
  float acc = 0.f;
  for (int j4 = 0; j4 < 512; ++j4) {
    float4 zz = zr[j4];
    float4 mm = mL[n * 512 + (j4 ^ (n & 7))];
    acc += zz.x * mm.x + zz.y * mm.y + zz.z * mm.z + zz.w * mm.w;
  }
  sim[((size_t)b * H_ + h) * NMEM + n0 + n] = acc * kScale;
}

// ---------------- top-8 per (b,h) ----------------
__global__ __launch_bounds__(256) void topk_kernel(const float* __restrict__ sim,
                                                   int* __restrict__ idx) {
  __shared__ float sL[1024];
  __shared__ float rv[256];
  __shared__ int ri[256];
  int tid = threadIdx.x;
  int h = blockIdx.x, b = blockIdx.y;
  const float* sp = sim + ((size_t)b * H_ + h) * NMEM;
#pragma unroll
  for (int r = 0; r < 4; ++r) sL[tid + r * 256] = sp[tid + r * 256];
  __syncthreads();
  for (int kk = 0; kk < 8; ++kk) {
    float bv = -INFINITY; int bi = 0x7fffffff;
#pragma unroll
    for (int r = 0; r < 4; ++r) {
      int i = tid + r * 256;
      float v = sL[i];
      if (v > bv || (v == bv && i < bi)) { bv = v; bi = i; }
    }
    rv[tid] = bv; ri[tid] = bi;
    __syncthreads();
    for (int s = 128; s > 0; s >>= 1) {
      if (tid < s) {
        float v2 = rv[tid + s]; int i2 = ri[tid + s];
        if (v2 > rv[tid] || (v2 == rv[tid] && i2 < ri[tid])) { rv[tid] = v2; ri[tid] = i2; }
      }
      __syncthreads();
    }
    if (tid == 0) { idx[((size_t)b * H_ + h) * KSEL + kk] = ri[0]; sL[ri[0]] = -INFINITY; }
    __syncthreads();
  }
}

// ---------------- memory-branch attention ----------------
__global__ __launch_bounds__(256) void memattn_kernel(const unsigned short* __restrict__ qbf,
                                                      const unsigned short* __restrict__ kvmem,
                                                      const int* __restrict__ idx,
                                                      unsigned short* __restrict__ omem) {
  __shared__ float kl[8][128];
  __shared__ float vl[8][128];
  __shared__ int selL[8];
  int tid = threadIdx.x;
  int b = blockIdx.z, h = blockIdx.y, t = blockIdx.x * 256 + tid;
  int kvh = h >> 1;
  if (tid < 8) selL[tid] = idx[((size_t)b * H_ + h) * KSEL + tid];
  __syncthreads();
  {
    int r = tid >> 5, c4 = (tid & 31) * 4;
    size_t rb = ((size_t)b * NMEM + selL[r]) * (size_t)KVSTR;
    ushort4 k4 = *(const ushort4*)(kvmem + rb + kvh * DH_ + c4);
    ushort4 v4 = *(const ushort4*)(kvmem + rb + KV_ * DH_ + kvh * DH_ + c4);
    kl[r][c4 + 0] = bf2f(k4.x); kl[r][c4 + 1] = bf2f(k4.y);
    kl[r][c4 + 2] = bf2f(k4.z); kl[r][c4 + 3] = bf2f(k4.w);
    vl[r][c4 + 0] = bf2f(v4.x); vl[r][c4 + 1] = bf2f(v4.y);
    vl[r][c4 + 2] = bf2f(v4.z); vl[r][c4 + 3] = bf2f(v4.w);
  }
  __syncthreads();
  float sc[8] = {0.f,0.f,0.f,0.f,0.f,0.f,0.f,0.f};
  const unsigned short* qr = qbf + (size_t)(b * T_ + t) * QKVSTR + h * DH_;
  for (int c = 0; c < 4; ++c) {
    const s16x8* qp = (const s16x8*)(qr + c * 32);
#pragma unroll
    for (int u = 0; u < 4; ++u) {
      s16x8 q8 = qp[u];
#pragma unroll
      for (int e = 0; e < 8; ++e) {
        float qv = bf2f((unsigned short)q8[e]);
        int d = c * 32 + u * 8 + e;
#pragma unroll
        for (int kk = 0; kk < 8; ++kk) sc[kk] += qv * kl[kk][d];
      }
    }
  }
  float sm[8], mx = -INFINITY;
#pragma unroll
  for (int kk = 0; kk < 8; ++kk) { sm[kk] = sc[kk] * kScale; mx = fmaxf(mx, sm[kk]); }
  float sum = 0.f;
#pragma unroll
  for (int kk = 0; kk < 8; ++kk) { sm[kk] = __expf(sm[kk] - mx); sum += sm[kk]; }
  float inv = 1.f / sum;
#pragma unroll
  for (int kk = 0; kk < 8; ++kk) sm[kk] *= inv;
  unsigned short* orow = omem + (size_t)(b * T_ + t) * D_ + h * DH_;
  for (int d = 0; d < 128; d += 4) {
    float o0 = 0.f, o1 = 0.f, o2 = 0.f, o3 = 0.f;
#pragma unroll
    for (int kk = 0; kk < 8; ++kk) {
      float w = sm[kk];
      o0 += w * vl[kk][d + 0];
      o1 += w * vl[kk][d + 1];
      o2 += w * vl[kk][d + 2];
      o3 += w * vl[kk][d + 3];
    }
    uint2 pk;
    pk.x = (unsigned)f2bf(o0) | ((unsigned)f2bf(o1) << 16);
    pk.y = (unsigned)f2bf(o2) | ((unsigned)f2bf(o3) << 16);
    *(uint2*)(orow + d) = pk;
  }
}

// ---------------- gate ----------------
__global__ __launch_bounds__(256) void gate_kernel(const float* __restrict__ hs,
                                                   const float* __restrict__ Wg,
                                                   const float* __restrict__ bg,
                                                   float* __restrict__ g) {
  int gid = blockIdx.x * 256 + threadIdx.x;
  int row = gid >> 6, lane = gid & 63;
  const float4* hr = (const float4*)(hs + (size_t)row * D_);
  const float4* wg4 = (const float4*)Wg;
  float acc = 0.f;
#pragma unroll
  for (int it = 0; it < 8; ++it) {
    float4 hv = hr[lane + it * 64], wv = wg4[lane + it * 64];
    acc += hv.x * wv.x + hv.y * wv.y + hv.z * wv.z + hv.w * wv.w;
  }
#pragma unroll
  for (int off = 1; off < 64; off <<= 1) acc += __shfl_xor(acc, off);
  if (lane == 0) g[row] = 1.f / (1.f + __expf(-(acc + bg[0])));
}

// ---------------- local sliding-window attention ----------------
__global__ __launch_bounds__(256) void localattn_kernel(const unsigned short* __restrict__ qbf,
                                                        const unsigned short* __restrict__ kbf,
                                                        const unsigned short* __restrict__ vbf,
                                                        unsigned short* __restrict__ olocal) {
  __shared__ __align__(16) unsigned short pl[4][16][40];
  const int tid = threadIdx.x;
  const int w = tid >> 6, lane = tid & 63;
  const int tb = blockIdx.x * 64;
  const int h = blockIdx.y, b = blockIdx.z;
  const int kvh = h >> 1;
  const int t0 = tb + w * 16;
  const int l15 = lane & 15, lg = lane >> 4;

  s16x8 qf[4];
  {
    const unsigned short* qb = qbf + ((size_t)(b * T_ + t0 + l15) * QKVSTR) + h * DH_ + lg * 8;
#pragma unroll
    for (int kb = 0; kb < 4; ++kb) qf[kb] = *(const s16x8*)(qb + kb * 32);
  }
  f32x4 of[8];
#pragma unroll
  for (int nb = 0; nb < 8; ++nb) of[nb] = fzero4();
  float m_r[4] = {-INFINITY, -INFINITY, -INFINITY, -INFINITY};
  float l_r[4] = {0.f, 0.f, 0.f, 0.f};

  int sstart = t0 - (WWIN - 1);
  if (sstart < 0) sstart = 0;
  sstart &= ~31;
  for (int s0 = sstart; s0 <= t0 + 15; s0 += 32) {
    f32x4 sc[2];
    sc[0] = fzero4(); sc[1] = fzero4();
    const unsigned short* kb0 = kbf + ((size_t)(b * T_ + s0 + l15) * QKVSTR) + kvh * DH_ + lg * 8;
#pragma unroll
    for (int cb = 0; cb < 2; ++cb) {
#pragma unroll
      for (int kb = 0; kb < 4; ++kb) {
        s16x8 kf = *(const s16x8*)(kb0 + (size_t)cb * 16 * QKVSTR + kb * 32);
        sc[cb] = __builtin_amdgcn_mfma_f32_16x16x32_bf16(qf[kb], kf, sc[cb], 0, 0, 0);
      }
    }
    float pv[2][4];
#pragma unroll
    for (int j = 0; j < 4; ++j) {
      int t = t0 + lg * 4 + j;
      int s_a = s0 + l15, s_b = s_a + 16;
      float va = sc[0][j] * kScale;
      float vb = sc[1][j] * kScale;
      va = (s_a <= t && s_a + (WWIN - 1) >= t) ? va : -INFINITY;
      vb = (s_b <= t && s_b + (WWIN - 1) >= t) ? vb : -INFINITY;
      float mx = fmaxf(va, vb);
#pragma unroll
      for (int off = 1; off < 16; off <<= 1) mx = fmaxf(mx, __shfl_xor(mx, off));
      float mn = fmaxf(m_r[j], mx);
      float alpha, pa, pb;
      if (mn == -INFINITY) { alpha = 1.f; pa = 0.f; pb = 0.f; }
      else {
        alpha = __expf(m_r[j] - mn);
        pa = __expf(va - mn);
        pb = __expf(vb - mn);
      }
      m_r[j] = mn;
      float rs = pa + pb;
#pragma unroll
      for (int off = 1; off < 16; off <<= 1) rs += __shfl_xor(rs, off);
      l_r[j] = l_r[j] * alpha + rs;
#pragma unroll
      for (int nb = 0; nb < 8; ++nb) of[nb][j] *= alpha;
      pv[0][j] = pa; pv[1][j] = pb;
    }
#pragma unroll
    for (int cb = 0; cb < 2; ++cb)
#pragma unroll
      for (int j = 0; j < 4; ++j)
        pl[w][lg * 4 + j][cb * 16 + l15] = f2bf(pv[cb][j]);
    asm volatile("s_waitcnt lgkmcnt(0)" ::: "memory");
    __builtin_amdgcn_sched_barrier(0);
    s16x8 pa8 = *(const s16x8*)&pl[w][l15][lg * 8];
    const unsigned short* vb0 = vbf + ((size_t)(b * T_ + s0 + lg * 8) * QKVSTR) + kvh * DH_ + l15;
#pragma unroll
    for (int nb = 0; nb < 8; ++nb) {
      s16x8 vf;
#pragma unroll
      for (int jj = 0; jj < 8; ++jj) vf[jj] = (short)vb0[(size_t)jj * QKVSTR + nb * 16];
      of[nb] = __builtin_amdgcn_mfma_f32_16x16x32_bf16(pa8, vf, of[nb], 0, 0, 0);
    }
  }
  float inv[4];
#pragma unroll
  for (int j = 0; j < 4; ++j) inv[j] = 1.f / l_r[j];
#pragma unroll
  for (int nb = 0; nb < 8; ++nb)
#pragma unroll
    for (int j = 0; j < 4; ++j) {
      int t = t0 + lg * 4 + j;
      olocal[(size_t)(b * T_ + t) * QKVSTR + h * DH_ + nb * 16 + l15] = f2bf(of[nb][j] * inv[j]);
    }
}

// ---------------- host launcher ----------------
extern "C" void kernel_launch(void* const* d_in, const int* in_sizes, int n_in,
                              void* d_out, int out_size, void* d_ws, size_t ws_size,
                              hipStream_t stream) {
  const float* hs   = (const float*)d_in[0];
  const float* cosp = (const float*)d_in[1];
  const float* sinp = (const float*)d_in[2];
  const float* mem  = (const float*)d_in[3];
  const float* Wq   = (const float*)d_in[4];
  const float* Wk   = (const float*)d_in[5];
  const float* Wv   = (const float*)d_in[6];
  const float* Wo   = (const float*)d_in[7];
  const float* Wg   = (const float*)d_in[8];
  const float* bg   = (const float*)d_in[9];
  float* out = (float*)d_out;

  char* p = (char*)d_ws;
  auto alloc = [&](size_t bytes) { char* r = p; p += (bytes + 255) & ~(size_t)255; return r; };
  float* qc     = (float*)alloc((size_t)B_ * H_ * DH_ * 4);
  float* gbuf   = (float*)alloc((size_t)BT * 4);
  float* zbuf   = (float*)alloc((size_t)B_ * H_ * D_ * 4);
  float* simbuf = (float*)alloc((size_t)B_ * H_ * NMEM * 4);
  int*   idxbuf = (int*)alloc((size_t)B_ * H_ * KSEL * 4);
  unsigned short* hs_bf   = (unsigned short*)alloc((size_t)BT * D_ * 2);       // -> o_mem bf16 later
  unsigned short* qkv_raw = (unsigned short*)alloc((size_t)BT * QKVSTR * 2);   // q|k|v merged; q -> o_local in place
  unsigned short* wbig    = (unsigned short*)alloc((size_t)2 * D_ * D_ * 2);   // Wq|Wk|Wv stack -> Wo reuses head
  unsigned short* mem_bf  = (unsigned short*)alloc((size_t)B_ * NMEM * D_ * 2); // -> Cr/Sr later
  unsigned short* kvmem   = (unsigned short*)alloc((size_t)B_ * NMEM * KVSTR * 2);

  // C/S partials live in d_out (33.55 MB; fully rewritten by final GEMM)
  float* Cp = (float*)d_out;
  float* Sp = Cp + (size_t)8 * B_ * DH_ * D_;
  float* Cr = (float*)mem_bf;
  float* Sr = Cr + (size_t)B_ * DH_ * D_;
  unsigned short* omem_bf = hs_bf;

  // 1) conversions + merged QKV projection (256^2 8-phase)
  conv_kernel<<<(BT * D_ / 4 + 255) / 256, 256, 0, stream>>>(hs, hs_bf, BT * D_);
  conv_kernel<<<(D_ * D_ / 4 + 255) / 256, 256, 0, stream>>>(Wq, wbig, D_ * D_);
  conv_kernel<<<(KV_ * DH_ * D_ / 4 + 255) / 256, 256, 0, stream>>>(Wk, wbig + (size_t)D_ * D_, KV_ * DH_ * D_);
  conv_kernel<<<(KV_ * DH_ * D_ / 4 + 255) / 256, 256, 0, stream>>>(Wv, wbig + (size_t)D_ * D_ + (size_t)KV_ * DH_ * D_, KV_ * DH_ * D_);
  gemm256<0><<<dim3(QKVSTR / 256, BT / 256), 512, 0, stream>>>(hs_bf, wbig, QKVSTR, D_, D_, QKVSTR, qkv_raw, nullptr, nullptr, nullptr);
  // kvmem = mem_bf @ (Wk|Wv)^T  (128-tile kernel: better grid for this shape)
  conv_kernel<<<(B_ * NMEM * D_ / 4 + 255) / 256, 256, 0, stream>>>(mem, mem_bf, B_ * NMEM * D_);
  gemm_bt<0><<<dim3(KVSTR / 128, (B_ * NMEM) / 128), 256, 0, stream>>>(mem_bf, wbig + (size_t)D_ * D_, KVSTR, D_, D_, KVSTR, kvmem, nullptr, nullptr, nullptr);

  // 2) in-place RoPE
  rope_ip_kernel<<<(BT * D_ / 16 + 255) / 256, 256, 0, stream>>>(qkv_raw, cosp, sinp, 10, QKVSTR, BT * D_ / 16);
  rope_ip_kernel<<<(BT * KV_ * DH_ / 16 + 255) / 256, 256, 0, stream>>>(qkv_raw + D_, cosp, sinp, 9, QKVSTR, BT * KV_ * DH_ / 16);

  // 3) exact-fp32 selection path
  cs_kernel<<<dim3(D_ / 128, DH_ / 32, B_ * 8), 256, 0, stream>>>(hs, cosp, sinp, Cp, Sp);
  reduce_cs_kernel<<<(B_ * DH_ * D_ / 4) / 256, 256, 0, stream>>>((const float4*)Cp, (const float4*)Sp, (float4*)Cr, (float4*)Sr);
  qchunk_kernel<<<(B_ * H_ * DH_) / 4, 256, 0, stream>>>(Wq, Cr, Sr, qc);
  zk_kernel<<<dim3(D_ / 256, H_, B_), 256, 0, stream>>>(qc, Wk, zbuf);
  sim_kernel<<<dim3(NMEM / 16, B_), 256, 0, stream>>>(zbuf, mem, simbuf);
  topk_kernel<<<dim3(H_, B_), 256, 0, stream>>>(simbuf, idxbuf);

  // 4) memory-branch attention -> o_mem bf16 (reuses hs_bf)
  memattn_kernel<<<dim3(T_ / 256, H_, B_), 256, 0, stream>>>(qkv_raw, kvmem, idxbuf, omem_bf);

  // 5) gate
  gate_kernel<<<BT / 4, 256, 0, stream>>>(hs, Wg, bg, gbuf);

  // 6) local sliding-window attention (writes o_local in place over q section)
  localattn_kernel<<<dim3(T_ / 64, H_, B_), 256, 0, stream>>>(qkv_raw, qkv_raw + D_, qkv_raw + D_ + KV_ * DH_, qkv_raw);

  // 7) Wo projection + final combine (256^2 8-phase, d_out pure write)
  conv_kernel<<<(D_ * D_ / 4 + 255) / 256, 256, 0, stream>>>(Wo, wbig, D_ * D_);
  gemm256<1><<<dim3(D_ / 256, BT / 256), 512, 0, stream>>>(qkv_raw, wbig, D_, D_, QKVSTR, D_, nullptr, gbuf, omem_bf, out);
}